// Round 9
// baseline (170.913 us; speedup 1.0000x reference)
//
#include <hip/hip_runtime.h>
#include <math.h>

#define BATCH 4
#define C 128
#define HW 4096
#define G 8
#define CPG 16
#define NH 4
#define HD 32
#define EPS 1e-5f
#define SCALE 0.08838834764831845f   // 128^-0.5
#define LOG2E 1.44269504088896340f
#define KP 44                         // attn K/V LDS pitch (ushorts): 22 banks, <=2-way
#define GP 136                        // gemm LDS pitch (ushorts): 16B-aligned rows

typedef unsigned int uint;
typedef unsigned short ushort;
typedef __attribute__((ext_vector_type(8))) short bf16x8;   // 8 bf16 (4 VGPRs)
typedef __attribute__((ext_vector_type(4))) float f32x4;

__device__ __forceinline__ ushort f2bf(float x) {
  uint u = __float_as_uint(x);
  u += 0x7fff + ((u >> 16) & 1);   // RNE
  return (ushort)(u >> 16);
}
__device__ __forceinline__ ushort f2bf_r(float x) {   // round-half-away, 2 insts
  return (ushort)((__float_as_uint(x) + 0x8000u) >> 16);
}
__device__ __forceinline__ float bf2f(ushort h) {
  return __uint_as_float(((uint)h) << 16);
}
// pack two f32 -> bf16 pair (a low). gfx950: single v_cvt_pk_bf16_f32.
__device__ __forceinline__ uint pk(float a, float b) {
#if __has_builtin(__builtin_amdgcn_cvt_pk_bf16_f32)
  auto r = __builtin_amdgcn_cvt_pk_bf16_f32(a, b);
  union { decltype(r) v; uint u; } x;
  x.v = r;
  return x.u;
#else
  uint ua = __float_as_uint(a) + 0x8000u;
  uint ub = __float_as_uint(b) + 0x8000u;
  return __builtin_amdgcn_perm(ub, ua, 0x07060302);
#endif
}
__device__ __forceinline__ bf16x8 as_bf(uint4 u) {
  union { uint4 a; bf16x8 b; } x; x.a = u; return x.b;
}
__device__ __forceinline__ float fexp2(float x) {
#if __has_builtin(__builtin_amdgcn_exp2f)
  return __builtin_amdgcn_exp2f(x);   // raw v_exp_f32
#else
  return __exp2f(x);
#endif
}

// ---------------- GN pass 1: deterministic partials, plain stores ----------------
__global__ __launch_bounds__(256) void gn_part(
    const float* __restrict__ x, float* __restrict__ stats) {
  const int bg = blockIdx.x >> 3, chunk = blockIdx.x & 7;
  const float* xp = x + (size_t)bg * (CPG * HW) + chunk * 8192;
  const int tid = threadIdx.x;
  float s = 0.f, ss = 0.f;
  #pragma unroll
  for (int j = 0; j < 8; j++) {
    float4 v = ((const float4*)xp)[j * 256 + tid];
    s += (v.x + v.y) + (v.z + v.w);
    ss += (v.x * v.x + v.y * v.y) + (v.z * v.z + v.w * v.w);
  }
  #pragma unroll
  for (int off = 32; off; off >>= 1) {
    s  += __shfl_down(s, off);
    ss += __shfl_down(ss, off);
  }
  __shared__ float rs[4], rss[4];
  const int lane = tid & 63, wid = tid >> 6;
  if (lane == 0) { rs[wid] = s; rss[wid] = ss; }
  __syncthreads();
  if (tid == 0) {
    stats[(bg * 8 + chunk) * 2]     = (rs[0] + rs[1]) + (rs[2] + rs[3]);
    stats[(bg * 8 + chunk) * 2 + 1] = (rss[0] + rss[1]) + (rss[2] + rss[3]);
  }
}

// ---------------- GN pass 2: reduce 8 partials, normalize, write bf16 xn ----------------
__global__ __launch_bounds__(256) void gn_apply(
    const float* __restrict__ x, const float* __restrict__ w,
    const float* __restrict__ b, const float* __restrict__ stats,
    ushort* __restrict__ xnb) {
  const int c = blockIdx.x, batch = blockIdx.y;
  const int bg = batch * G + (c >> 4);
  float s = 0.f, ss = 0.f;
  #pragma unroll
  for (int k = 0; k < 8; k++) {
    s  += stats[(bg * 8 + k) * 2];
    ss += stats[(bg * 8 + k) * 2 + 1];
  }
  const float mean = s * (1.0f / 65536.0f);
  const float var  = ss * (1.0f / 65536.0f) - mean * mean;
  const float inv  = rsqrtf(var + EPS);
  const float ca = w[c] * inv;
  const float cb = b[c] - mean * ca;
  const size_t base = ((size_t)batch * C + c) * HW;
  const float* xp = x + base;
  ushort* op = xnb + base;
  const int tid = threadIdx.x;
  #pragma unroll
  for (int j = 0; j < 4; j++) {
    int i = (j * 256 + tid) * 4;
    float4 v = *(const float4*)&xp[i];
    uint2 u;
    u.x = pk(fmaf(v.x, ca, cb), fmaf(v.y, ca, cb));
    u.y = pk(fmaf(v.z, ca, cb), fmaf(v.w, ca, cb));
    *(uint2*)&op[i] = u;
  }
}

// ---------------- MFMA GEMM: qkv = W(384x128) @ xn(128 x HW) ----------------
// single-stage full-K panels (64x128 each), one barrier, 16 MFMA/wave
__global__ __launch_bounds__(256) void qkv_gemm(
    const ushort* __restrict__ xnb, const float* __restrict__ w,
    const float* __restrict__ bias, ushort* __restrict__ qkvb) {
  const int b = blockIdx.z, m0 = blockIdx.y * 64, n0 = blockIdx.x * 64;
  const int tid = threadIdx.x, lane = tid & 63, wv = tid >> 6;
  const int li = lane & 15, g = lane >> 4;
  __shared__ ushort Ws[64][GP];
  __shared__ ushort Xs[64][GP];

  // stage W: thread -> (row, 32-col chunk); fp32->bf16
  {
    const int row = tid >> 2, c0 = (tid & 3) * 32;
    const float* wr = w + (size_t)(m0 + row) * C + c0;
    #pragma unroll
    for (int k = 0; k < 4; k++) {
      float4 f0 = ((const float4*)wr)[k * 2];
      float4 f1 = ((const float4*)wr)[k * 2 + 1];
      uint4 u = {pk(f0.x, f0.y), pk(f0.z, f0.w), pk(f1.x, f1.y), pk(f1.z, f1.w)};
      *(uint4*)&Ws[row][c0 + k * 8] = u;
    }
  }
  // stage X transposed: Xs[n][c]
  {
    const int nX = tid & 63, c0 = (tid >> 6) * 32;
    const ushort* xb = xnb + (size_t)(b * C + c0) * HW + n0 + nX;
    #pragma unroll
    for (int k = 0; k < 4; k++) {
      ushort t8[8];
      #pragma unroll
      for (int j = 0; j < 8; j++) t8[j] = xb[(size_t)(k * 8 + j) * HW];
      uint4 u;
      u.x = t8[0] | ((uint)t8[1] << 16);
      u.y = t8[2] | ((uint)t8[3] << 16);
      u.z = t8[4] | ((uint)t8[5] << 16);
      u.w = t8[6] | ((uint)t8[7] << 16);
      *(uint4*)&Xs[nX][c0 + k * 8] = u;
    }
  }
  __syncthreads();

  f32x4 acc[4];
  #pragma unroll
  for (int nt = 0; nt < 4; nt++) acc[nt] = (f32x4){0.f, 0.f, 0.f, 0.f};
  #pragma unroll
  for (int kk = 0; kk < 4; kk++) {
    bf16x8 af = *(const bf16x8*)&Ws[wv * 16 + li][kk * 32 + g * 8];
    #pragma unroll
    for (int nt = 0; nt < 4; nt++) {
      bf16x8 bfr = *(const bf16x8*)&Xs[nt * 16 + li][kk * 32 + g * 8];
      acc[nt] = __builtin_amdgcn_mfma_f32_16x16x32_bf16(af, bfr, acc[nt], 0, 0, 0);
    }
  }
  const int ob = m0 + wv * 16 + g * 4;
  #pragma unroll
  for (int r = 0; r < 4; r++) {
    float bi = bias[ob + r];
    #pragma unroll
    for (int nt = 0; nt < 4; nt++) {
      qkvb[(size_t)(b * 3 * C + ob + r) * HW + n0 + nt * 16 + li] = f2bf(acc[nt][r] + bi);
    }
  }
}

// ---------------- K prep: KT[bh][e][c] (c contiguous), vectorized ----------------
__global__ __launch_bounds__(256) void kvprep_kernel(
    const ushort* __restrict__ qkvb, ushort* __restrict__ kt) {
  const int bh = blockIdx.y, b = bh >> 2, h = bh & 3;
  const int e0 = blockIdx.x * 64;
  const ushort* kp = qkvb + (size_t)(b * 3 * C + C + h * HD) * HW;
  ushort* ktp = kt + (size_t)bh * HW * HD;
  const int t = threadIdx.x;

  __shared__ ushort Kt[32][66];
  {
    const int c = t >> 3, e8 = (t & 7) * 8;
    *(uint4*)&Kt[c][e8] = *(const uint4*)&kp[(size_t)c * HW + e0 + e8];
  }
  __syncthreads();
  {
    const int e = t >> 2, c0 = (t & 3) * 8;
    ushort o[8];
    #pragma unroll
    for (int j = 0; j < 8; j++) o[j] = Kt[c0 + j][e];
    uint4 u;
    u.x = o[0] | ((uint)o[1] << 16);
    u.y = o[2] | ((uint)o[3] << 16);
    u.z = o[4] | ((uint)o[5] << 16);
    u.w = o[6] | ((uint)o[7] << 16);
    *(uint4*)&ktp[(size_t)(e0 + e) * HD + c0] = u;
  }
}

// ---------------- MFMA flash attention: LDS-shared K/V + split-K 2-way, 8-wave blocks ----------------
// OP merge scratch UNIONed over Ks/Vs (only used post-loop) -> 38.9 KB LDS -> 4 blocks/CU.
// K/V pitch 44 ushorts (22 banks): all fragment reads <=2-way (free). uint2 LDS ops (8B-aligned).
__global__ __launch_bounds__(512, 8) void attn_kernel(
    ushort* __restrict__ qkv, const ushort* __restrict__ kt) {
  const int bh = blockIdx.y, b = bh >> 2, h = bh & 3;
  const int tid = threadIdx.x, lane = tid & 63, wv = tid >> 6;
  const int li = lane & 15, g = lane >> 4;
  const int grp = wv >> 2, w4 = wv & 3;
  ushort* qp = qkv + (size_t)(b * 3 * C + h * HD) * HW;
  const ushort* vpl = qkv + (size_t)(b * 3 * C + 2 * C + h * HD) * HW;
  const ushort* ktp = kt + (size_t)bh * HW * HD;
  const int d0 = blockIdx.x * 128 + w4 * 32;

  struct SmemT {
    union {
      struct { ushort Ks[2][2][32][KP]; ushort Vs[2][2][32][KP]; } t;  // 22528 B
      float OP[8][64][19];                                             // 38912 B
    };
  };
  __shared__ SmemT sm;

  // Q B-fragments (2 d-tiles), prescaled by SCALE*log2(e)
  const float qs = SCALE * LOG2E;
  bf16x8 qf[2];
  #pragma unroll
  for (int dt = 0; dt < 2; dt++) {
    int d = d0 + dt * 16 + li;
    float qv[8];
    #pragma unroll
    for (int j = 0; j < 8; j++)
      qv[j] = bf2f(qp[(size_t)(g * 8 + j) * HW + d]) * qs;
    uint4 qu = {pk(qv[0], qv[1]), pk(qv[2], qv[3]), pk(qv[4], qv[5]), pk(qv[6], qv[7])};
    qf[dt] = as_bf(qu);
  }

  f32x4 O[2][2];
  #pragma unroll
  for (int dt = 0; dt < 2; dt++)
    #pragma unroll
    for (int ct = 0; ct < 2; ct++) O[dt][ct] = (f32x4){0.f, 0.f, 0.f, 0.f};
  f32x4 lacc[2] = {(f32x4){0.f, 0.f, 0.f, 0.f}, (f32x4){0.f, 0.f, 0.f, 0.f}};
  const uint one2 = 0x3F803F80u;
  const bf16x8 ones = as_bf((uint4){one2, one2, one2, one2});

  // staging: group-local threads 0..127 stage K, 128..255 stage V
  const int gt = tid & 255;
  const bool isK = gt < 128;
  const int t2 = gt & 127;
  const int srow = t2 >> 2, scol8 = (t2 & 3) * 8;
  const ushort* gK = ktp + (size_t)(grp * 64) * 1024 + t2 * 8;       // + n*1024
  const ushort* gV = vpl + (size_t)srow * HW + grp * 2048 + scol8;   // + n*32

  uint4 st = isK ? *(const uint4*)&gK[0] : *(const uint4*)&gV[0];
  if (isK) {
    *(uint2*)&sm.t.Ks[grp][0][srow][scol8]     = (uint2){st.x, st.y};
    *(uint2*)&sm.t.Ks[grp][0][srow][scol8 + 4] = (uint2){st.z, st.w};
  } else {
    *(uint2*)&sm.t.Vs[grp][0][srow][scol8]     = (uint2){st.x, st.y};
    *(uint2*)&sm.t.Vs[grp][0][srow][scol8 + 4] = (uint2){st.z, st.w};
  }
  st = isK ? *(const uint4*)&gK[1024] : *(const uint4*)&gV[32];
  __syncthreads();

  for (int it = 0; it < 64; it++) {
    const int cur = it & 1, nxt = cur ^ 1;
    // store tile it+1 (loaded last iter) into the other buffer
    if (isK) {
      *(uint2*)&sm.t.Ks[grp][nxt][srow][scol8]     = (uint2){st.x, st.y};
      *(uint2*)&sm.t.Ks[grp][nxt][srow][scol8 + 4] = (uint2){st.z, st.w};
    } else {
      *(uint2*)&sm.t.Vs[grp][nxt][srow][scol8]     = (uint2){st.x, st.y};
      *(uint2*)&sm.t.Vs[grp][nxt][srow][scol8 + 4] = (uint2){st.z, st.w};
    }

    // fragments from current buffer (all uint2, 8B-aligned, <=2-way banks)
    uint2 ka0 = *(const uint2*)&sm.t.Ks[grp][cur][li][g * 8];
    uint2 ka1 = *(const uint2*)&sm.t.Ks[grp][cur][li][g * 8 + 4];
    uint2 kb0 = *(const uint2*)&sm.t.Ks[grp][cur][16 + li][g * 8];
    uint2 kb1 = *(const uint2*)&sm.t.Ks[grp][cur][16 + li][g * 8 + 4];
    bf16x8 kf0 = as_bf((uint4){ka0.x, ka0.y, ka1.x, ka1.y});
    bf16x8 kf1 = as_bf((uint4){kb0.x, kb0.y, kb1.x, kb1.y});
    uint2 va0 = *(const uint2*)&sm.t.Vs[grp][cur][li][4 * g];
    uint2 va1 = *(const uint2*)&sm.t.Vs[grp][cur][li][16 + 4 * g];
    uint2 vb0 = *(const uint2*)&sm.t.Vs[grp][cur][16 + li][4 * g];
    uint2 vb1 = *(const uint2*)&sm.t.Vs[grp][cur][16 + li][16 + 4 * g];
    bf16x8 vf0 = as_bf((uint4){va0.x, va0.y, va1.x, va1.y});
    bf16x8 vf1 = as_bf((uint4){vb0.x, vb0.y, vb1.x, vb1.y});

    // prefetch tile it+2 into regs (wraps in-range on last iters: dead data)
    const int tn = (it + 2) & 63;
    st = isK ? *(const uint4*)&gK[(size_t)tn * 1024] : *(const uint4*)&gV[tn * 32];

    const f32x4 z = (f32x4){0.f, 0.f, 0.f, 0.f};
    #pragma unroll
    for (int dt = 0; dt < 2; dt++) {
      f32x4 s0 = __builtin_amdgcn_mfma_f32_16x16x32_bf16(kf0, qf[dt], z, 0, 0, 0);
      f32x4 s1 = __builtin_amdgcn_mfma_f32_16x16x32_bf16(kf1, qf[dt], z, 0, 0, 0);
      float p0 = fexp2(s0[0]), p1 = fexp2(s0[1]), p2 = fexp2(s0[2]), p3 = fexp2(s0[3]);
      float p4 = fexp2(s1[0]), p5 = fexp2(s1[1]), p6 = fexp2(s1[2]), p7 = fexp2(s1[3]);
      // sigma: k=g*8+{0..3} -> e=4g+{0..3}; k=g*8+{4..7} -> e=16+4g+{0..3}
      uint4 pu = {pk(p0, p1), pk(p2, p3), pk(p4, p5), pk(p6, p7)};
      bf16x8 pf = as_bf(pu);
      lacc[dt] = __builtin_amdgcn_mfma_f32_16x16x32_bf16(ones, pf, lacc[dt], 0, 0, 0);
      O[dt][0] = __builtin_amdgcn_mfma_f32_16x16x32_bf16(vf0, pf, O[dt][0], 0, 0, 0);
      O[dt][1] = __builtin_amdgcn_mfma_f32_16x16x32_bf16(vf1, pf, O[dt][1], 0, 0, 0);
    }
    __syncthreads();
  }

  // ---- split-K merge with partner wave (w ^ 4); wave writes channel half ct=grp ----
  // (Ks/Vs dead from here; OP aliases them — barrier above separates the phases)
  #pragma unroll
  for (int dt = 0; dt < 2; dt++) {
    #pragma unroll
    for (int ct = 0; ct < 2; ct++)
      #pragma unroll
      for (int r = 0; r < 4; r++) sm.OP[wv][lane][dt * 8 + ct * 4 + r] = O[dt][ct][r];
    sm.OP[wv][lane][16 + dt] = lacc[dt][0];
  }
  __syncthreads();
  const int pw = wv ^ 4;
  #pragma unroll
  for (int dt = 0; dt < 2; dt++) {
    const float inv = 1.0f / (lacc[dt][0] + sm.OP[pw][lane][16 + dt]);
    const int d = d0 + dt * 16 + li;
    #pragma unroll
    for (int r = 0; r < 4; r++) {
      float val = O[dt][grp][r] + sm.OP[pw][lane][dt * 8 + grp * 4 + r];
      qp[(size_t)(grp * 16 + g * 4 + r) * HW + d] = f2bf_r(val * inv);
    }
  }
}

// ---------------- MFMA GEMM proj + bias + bf16 residual, fp32 out ----------------
// same single-stage full-K structure as qkv_gemm
__global__ __launch_bounds__(256) void proj_gemm(
    const ushort* __restrict__ qkvb, const float* __restrict__ w,
    const float* __restrict__ bias, const ushort* __restrict__ xnb, float* __restrict__ out) {
  const int b = blockIdx.z, m0 = blockIdx.y * 64, n0 = blockIdx.x * 64;
  const int tid = threadIdx.x, lane = tid & 63, wv = tid >> 6;
  const int li = lane & 15, g = lane >> 4;
  __shared__ ushort Ws[64][GP];
  __shared__ ushort Xs[64][GP];

  {
    const int row = tid >> 2, c0 = (tid & 3) * 32;
    const float* wr = w + (size_t)(m0 + row) * C + c0;
    #pragma unroll
    for (int k = 0; k < 4; k++) {
      float4 f0 = ((const float4*)wr)[k * 2];
      float4 f1 = ((const float4*)wr)[k * 2 + 1];
      uint4 u = {pk(f0.x, f0.y), pk(f0.z, f0.w), pk(f1.x, f1.y), pk(f1.z, f1.w)};
      *(uint4*)&Ws[row][c0 + k * 8] = u;
    }
  }
  {
    const int nX = tid & 63, c0 = (tid >> 6) * 32;
    const ushort* xb = qkvb + (size_t)(b * 3 * C + c0) * HW + n0 + nX;
    #pragma unroll
    for (int k = 0; k < 4; k++) {
      ushort t8[8];
      #pragma unroll
      for (int j = 0; j < 8; j++) t8[j] = xb[(size_t)(k * 8 + j) * HW];
      uint4 u;
      u.x = t8[0] | ((uint)t8[1] << 16);
      u.y = t8[2] | ((uint)t8[3] << 16);
      u.z = t8[4] | ((uint)t8[5] << 16);
      u.w = t8[6] | ((uint)t8[7] << 16);
      *(uint4*)&Xs[nX][c0 + k * 8] = u;
    }
  }
  __syncthreads();

  f32x4 acc[4];
  #pragma unroll
  for (int nt = 0; nt < 4; nt++) acc[nt] = (f32x4){0.f, 0.f, 0.f, 0.f};
  #pragma unroll
  for (int kk = 0; kk < 4; kk++) {
    bf16x8 af = *(const bf16x8*)&Ws[wv * 16 + li][kk * 32 + g * 8];
    #pragma unroll
    for (int nt = 0; nt < 4; nt++) {
      bf16x8 bfr = *(const bf16x8*)&Xs[nt * 16 + li][kk * 32 + g * 8];
      acc[nt] = __builtin_amdgcn_mfma_f32_16x16x32_bf16(af, bfr, acc[nt], 0, 0, 0);
    }
  }
  const int ob = m0 + wv * 16 + g * 4;
  #pragma unroll
  for (int r = 0; r < 4; r++) {
    float bi = bias[ob + r];
    #pragma unroll
    for (int nt = 0; nt < 4; nt++) {
      size_t idx = (size_t)(b * C + ob + r) * HW + n0 + nt * 16 + li;
      out[idx] = acc[nt][r] + bi + bf2f(xnb[idx]);
    }
  }
}

extern "C" void kernel_launch(void* const* d_in, const int* in_sizes, int n_in,
                              void* d_out, int out_size, void* d_ws, size_t ws_size,
                              hipStream_t stream) {
  const float* x     = (const float*)d_in[0];
  const float* gn_w  = (const float*)d_in[1];
  const float* gn_b  = (const float*)d_in[2];
  const float* qkv_w = (const float*)d_in[3];
  const float* qkv_b = (const float*)d_in[4];
  const float* pw    = (const float*)d_in[5];
  const float* pb    = (const float*)d_in[6];
  float* out = (float*)d_out;

  float*  stats = (float*)d_ws;                              // 512 floats (pad to 4 KB)
  ushort* xnb   = (ushort*)((char*)d_ws + 4096);             // 4 MB  bf16 [b][c][hw]
  ushort* qkvb  = xnb + (size_t)BATCH * C * HW;              // 12 MB bf16
  ushort* kt    = qkvb + (size_t)BATCH * 3 * C * HW;         // 4 MB  [bh][e][c]

  gn_part<<<dim3(256), dim3(256), 0, stream>>>(x, stats);
  gn_apply<<<dim3(C, BATCH), dim3(256), 0, stream>>>(x, gn_w, gn_b, stats, xnb);
  qkv_gemm<<<dim3(HW / 64, 6, BATCH), dim3(256), 0, stream>>>(xnb, qkv_w, qkv_b, qkvb);
  kvprep_kernel<<<dim3(HW / 64, BATCH * NH), dim3(256), 0, stream>>>(qkvb, kt);
  attn_kernel<<<dim3(HW / 128, BATCH * NH), dim3(512), 0, stream>>>(qkvb, kt);
  proj_gemm<<<dim3(HW / 64, 2, BATCH), dim3(256), 0, stream>>>(qkvb, pw, pb, xnb, out);
}

// Round 10
// 165.341 us; speedup vs baseline: 1.0337x; 1.0337x over previous
//
#include <hip/hip_runtime.h>
#include <math.h>

#define BATCH 4
#define C 128
#define HW 4096
#define G 8
#define CPG 16
#define NH 4
#define HD 32
#define EPS 1e-5f
#define SCALE 0.08838834764831845f   // 128^-0.5
#define LOG2E 1.44269504088896340f
#define KP 40                         // attn K/V LDS pitch (ushorts), r8-proven
#define GP 136                        // gemm LDS pitch (ushorts): 16B-aligned rows

typedef unsigned int uint;
typedef unsigned short ushort;
typedef __attribute__((ext_vector_type(8))) short bf16x8;   // 8 bf16 (4 VGPRs)
typedef __attribute__((ext_vector_type(4))) float f32x4;

__device__ __forceinline__ ushort f2bf(float x) {
  uint u = __float_as_uint(x);
  u += 0x7fff + ((u >> 16) & 1);   // RNE
  return (ushort)(u >> 16);
}
__device__ __forceinline__ ushort f2bf_r(float x) {   // round-half-away, 2 insts
  return (ushort)((__float_as_uint(x) + 0x8000u) >> 16);
}
__device__ __forceinline__ float bf2f(ushort h) {
  return __uint_as_float(((uint)h) << 16);
}
// pack two f32 -> bf16 pair (a low). gfx950: single v_cvt_pk_bf16_f32.
__device__ __forceinline__ uint pk(float a, float b) {
#if __has_builtin(__builtin_amdgcn_cvt_pk_bf16_f32)
  auto r = __builtin_amdgcn_cvt_pk_bf16_f32(a, b);
  union { decltype(r) v; uint u; } x;
  x.v = r;
  return x.u;
#else
  uint ua = __float_as_uint(a) + 0x8000u;
  uint ub = __float_as_uint(b) + 0x8000u;
  return __builtin_amdgcn_perm(ub, ua, 0x07060302);
#endif
}
__device__ __forceinline__ bf16x8 as_bf(uint4 u) {
  union { uint4 a; bf16x8 b; } x; x.a = u; return x.b;
}
__device__ __forceinline__ float fexp2(float x) {
#if __has_builtin(__builtin_amdgcn_exp2f)
  return __builtin_amdgcn_exp2f(x);   // raw v_exp_f32
#else
  return __exp2f(x);
#endif
}

// ---------------- GN pass 1: deterministic partials, plain stores ----------------
__global__ __launch_bounds__(256) void gn_part(
    const float* __restrict__ x, float* __restrict__ stats) {
  const int bg = blockIdx.x >> 3, chunk = blockIdx.x & 7;
  const float* xp = x + (size_t)bg * (CPG * HW) + chunk * 8192;
  const int tid = threadIdx.x;
  float s = 0.f, ss = 0.f;
  #pragma unroll
  for (int j = 0; j < 8; j++) {
    float4 v = ((const float4*)xp)[j * 256 + tid];
    s += (v.x + v.y) + (v.z + v.w);
    ss += (v.x * v.x + v.y * v.y) + (v.z * v.z + v.w * v.w);
  }
  #pragma unroll
  for (int off = 32; off; off >>= 1) {
    s  += __shfl_down(s, off);
    ss += __shfl_down(ss, off);
  }
  __shared__ float rs[4], rss[4];
  const int lane = tid & 63, wid = tid >> 6;
  if (lane == 0) { rs[wid] = s; rss[wid] = ss; }
  __syncthreads();
  if (tid == 0) {
    stats[(bg * 8 + chunk) * 2]     = (rs[0] + rs[1]) + (rs[2] + rs[3]);
    stats[(bg * 8 + chunk) * 2 + 1] = (rss[0] + rss[1]) + (rss[2] + rss[3]);
  }
}

// ---------------- GN pass 2: reduce 8 partials, normalize, write bf16 xn ----------------
__global__ __launch_bounds__(256) void gn_apply(
    const float* __restrict__ x, const float* __restrict__ w,
    const float* __restrict__ b, const float* __restrict__ stats,
    ushort* __restrict__ xnb) {
  const int c = blockIdx.x, batch = blockIdx.y;
  const int bg = batch * G + (c >> 4);
  float s = 0.f, ss = 0.f;
  #pragma unroll
  for (int k = 0; k < 8; k++) {
    s  += stats[(bg * 8 + k) * 2];
    ss += stats[(bg * 8 + k) * 2 + 1];
  }
  const float mean = s * (1.0f / 65536.0f);
  const float var  = ss * (1.0f / 65536.0f) - mean * mean;
  const float inv  = rsqrtf(var + EPS);
  const float ca = w[c] * inv;
  const float cb = b[c] - mean * ca;
  const size_t base = ((size_t)batch * C + c) * HW;
  const float* xp = x + base;
  ushort* op = xnb + base;
  const int tid = threadIdx.x;
  #pragma unroll
  for (int j = 0; j < 4; j++) {
    int i = (j * 256 + tid) * 4;
    float4 v = *(const float4*)&xp[i];
    uint2 u;
    u.x = pk(fmaf(v.x, ca, cb), fmaf(v.y, ca, cb));
    u.y = pk(fmaf(v.z, ca, cb), fmaf(v.w, ca, cb));
    *(uint2*)&op[i] = u;
  }
}

// ---------------- MFMA GEMM: qkv = W(384x128) @ xn(128 x HW) ----------------
// single-stage full-K panels (64x128 each), one barrier, 16 MFMA/wave
__global__ __launch_bounds__(256) void qkv_gemm(
    const ushort* __restrict__ xnb, const float* __restrict__ w,
    const float* __restrict__ bias, ushort* __restrict__ qkvb) {
  const int b = blockIdx.z, m0 = blockIdx.y * 64, n0 = blockIdx.x * 64;
  const int tid = threadIdx.x, lane = tid & 63, wv = tid >> 6;
  const int li = lane & 15, g = lane >> 4;
  __shared__ ushort Ws[64][GP];
  __shared__ ushort Xs[64][GP];

  {
    const int row = tid >> 2, c0 = (tid & 3) * 32;
    const float* wr = w + (size_t)(m0 + row) * C + c0;
    #pragma unroll
    for (int k = 0; k < 4; k++) {
      float4 f0 = ((const float4*)wr)[k * 2];
      float4 f1 = ((const float4*)wr)[k * 2 + 1];
      uint4 u = {pk(f0.x, f0.y), pk(f0.z, f0.w), pk(f1.x, f1.y), pk(f1.z, f1.w)};
      *(uint4*)&Ws[row][c0 + k * 8] = u;
    }
  }
  {
    const int nX = tid & 63, c0 = (tid >> 6) * 32;
    const ushort* xb = xnb + (size_t)(b * C + c0) * HW + n0 + nX;
    #pragma unroll
    for (int k = 0; k < 4; k++) {
      ushort t8[8];
      #pragma unroll
      for (int j = 0; j < 8; j++) t8[j] = xb[(size_t)(k * 8 + j) * HW];
      uint4 u;
      u.x = t8[0] | ((uint)t8[1] << 16);
      u.y = t8[2] | ((uint)t8[3] << 16);
      u.z = t8[4] | ((uint)t8[5] << 16);
      u.w = t8[6] | ((uint)t8[7] << 16);
      *(uint4*)&Xs[nX][c0 + k * 8] = u;
    }
  }
  __syncthreads();

  f32x4 acc[4];
  #pragma unroll
  for (int nt = 0; nt < 4; nt++) acc[nt] = (f32x4){0.f, 0.f, 0.f, 0.f};
  #pragma unroll
  for (int kk = 0; kk < 4; kk++) {
    bf16x8 af = *(const bf16x8*)&Ws[wv * 16 + li][kk * 32 + g * 8];
    #pragma unroll
    for (int nt = 0; nt < 4; nt++) {
      bf16x8 bfr = *(const bf16x8*)&Xs[nt * 16 + li][kk * 32 + g * 8];
      acc[nt] = __builtin_amdgcn_mfma_f32_16x16x32_bf16(af, bfr, acc[nt], 0, 0, 0);
    }
  }
  const int ob = m0 + wv * 16 + g * 4;
  #pragma unroll
  for (int r = 0; r < 4; r++) {
    float bi = bias[ob + r];
    #pragma unroll
    for (int nt = 0; nt < 4; nt++) {
      qkvb[(size_t)(b * 3 * C + ob + r) * HW + n0 + nt * 16 + li] = f2bf(acc[nt][r] + bi);
    }
  }
}

// ---------------- K prep: KT[bh][e][c] (c contiguous), vectorized ----------------
__global__ __launch_bounds__(256) void kvprep_kernel(
    const ushort* __restrict__ qkvb, ushort* __restrict__ kt) {
  const int bh = blockIdx.y, b = bh >> 2, h = bh & 3;
  const int e0 = blockIdx.x * 64;
  const ushort* kp = qkvb + (size_t)(b * 3 * C + C + h * HD) * HW;
  ushort* ktp = kt + (size_t)bh * HW * HD;
  const int t = threadIdx.x;

  __shared__ ushort Kt[32][66];
  {
    const int c = t >> 3, e8 = (t & 7) * 8;
    *(uint4*)&Kt[c][e8] = *(const uint4*)&kp[(size_t)c * HW + e0 + e8];
  }
  __syncthreads();
  {
    const int e = t >> 2, c0 = (t & 3) * 8;
    ushort o[8];
    #pragma unroll
    for (int j = 0; j < 8; j++) o[j] = Kt[c0 + j][e];
    uint4 u;
    u.x = o[0] | ((uint)o[1] << 16);
    u.y = o[2] | ((uint)o[3] << 16);
    u.z = o[4] | ((uint)o[5] << 16);
    u.w = o[6] | ((uint)o[7] << 16);
    *(uint4*)&ktp[(size_t)(e0 + e) * HD + c0] = u;
  }
}

// ---------------- MFMA flash attention: LDS-shared K/V + split-K 2-way, 8-wave blocks ----------------
// r8 body (pitch 40, uint4 staging, ones-MFMA l) + OP unioned over tiles (38.9 KB)
// + __launch_bounds__(512,6): 85-reg budget fits the ~76-reg footprint (no spill),
// LDS allows 3 blocks/CU = 6 waves/SIMD.
__global__ __launch_bounds__(512, 6) void attn_kernel(
    ushort* __restrict__ qkv, const ushort* __restrict__ kt) {
  const int bh = blockIdx.y, b = bh >> 2, h = bh & 3;
  const int tid = threadIdx.x, lane = tid & 63, wv = tid >> 6;
  const int li = lane & 15, g = lane >> 4;
  const int grp = wv >> 2, w4 = wv & 3;
  ushort* qp = qkv + (size_t)(b * 3 * C + h * HD) * HW;
  const ushort* vpl = qkv + (size_t)(b * 3 * C + 2 * C + h * HD) * HW;
  const ushort* ktp = kt + (size_t)bh * HW * HD;
  const int d0 = blockIdx.x * 128 + w4 * 32;

  struct SmemT {
    union {
      struct { ushort Ks[2][2][32][KP]; ushort Vs[2][2][32][KP]; } t;  // 20480 B
      float OP[8][64][19];                                             // 38912 B
    };
  };
  __shared__ SmemT sm;

  // Q B-fragments (2 d-tiles), prescaled by SCALE*log2(e)
  const float qs = SCALE * LOG2E;
  bf16x8 qf[2];
  #pragma unroll
  for (int dt = 0; dt < 2; dt++) {
    int d = d0 + dt * 16 + li;
    float qv[8];
    #pragma unroll
    for (int j = 0; j < 8; j++)
      qv[j] = bf2f(qp[(size_t)(g * 8 + j) * HW + d]) * qs;
    uint4 qu = {pk(qv[0], qv[1]), pk(qv[2], qv[3]), pk(qv[4], qv[5]), pk(qv[6], qv[7])};
    qf[dt] = as_bf(qu);
  }

  f32x4 O[2][2];
  #pragma unroll
  for (int dt = 0; dt < 2; dt++)
    #pragma unroll
    for (int ct = 0; ct < 2; ct++) O[dt][ct] = (f32x4){0.f, 0.f, 0.f, 0.f};
  f32x4 lacc[2] = {(f32x4){0.f, 0.f, 0.f, 0.f}, (f32x4){0.f, 0.f, 0.f, 0.f}};
  const uint one2 = 0x3F803F80u;
  const bf16x8 ones = as_bf((uint4){one2, one2, one2, one2});

  // staging: group-local threads 0..127 stage K, 128..255 stage V
  const int gt = tid & 255;
  const bool isK = gt < 128;
  const int t2 = gt & 127;
  const int srow = t2 >> 2, scol8 = (t2 & 3) * 8;
  const ushort* gK = ktp + (size_t)(grp * 64) * 1024 + t2 * 8;       // + n*1024
  const ushort* gV = vpl + (size_t)srow * HW + grp * 2048 + scol8;   // + n*32

  uint4 st = isK ? *(const uint4*)&gK[0] : *(const uint4*)&gV[0];
  if (isK) *(uint4*)&sm.t.Ks[grp][0][srow][scol8] = st;
  else     *(uint4*)&sm.t.Vs[grp][0][srow][scol8] = st;
  st = isK ? *(const uint4*)&gK[1024] : *(const uint4*)&gV[32];
  __syncthreads();

  for (int it = 0; it < 64; it++) {
    const int cur = it & 1, nxt = cur ^ 1;
    // store tile it+1 (loaded last iter) into the other buffer
    if (isK) *(uint4*)&sm.t.Ks[grp][nxt][srow][scol8] = st;
    else     *(uint4*)&sm.t.Vs[grp][nxt][srow][scol8] = st;

    // fragments from current buffer
    bf16x8 kf0 = *(const bf16x8*)&sm.t.Ks[grp][cur][li][g * 8];
    bf16x8 kf1 = *(const bf16x8*)&sm.t.Ks[grp][cur][16 + li][g * 8];
    uint2 va0 = *(const uint2*)&sm.t.Vs[grp][cur][li][4 * g];
    uint2 va1 = *(const uint2*)&sm.t.Vs[grp][cur][li][16 + 4 * g];
    uint2 vb0 = *(const uint2*)&sm.t.Vs[grp][cur][16 + li][4 * g];
    uint2 vb1 = *(const uint2*)&sm.t.Vs[grp][cur][16 + li][16 + 4 * g];
    bf16x8 vf0 = as_bf((uint4){va0.x, va0.y, va1.x, va1.y});
    bf16x8 vf1 = as_bf((uint4){vb0.x, vb0.y, vb1.x, vb1.y});

    // prefetch tile it+2 into regs (wraps in-range on last iters: dead data)
    const int tn = (it + 2) & 63;
    st = isK ? *(const uint4*)&gK[(size_t)tn * 1024] : *(const uint4*)&gV[tn * 32];

    const f32x4 z = (f32x4){0.f, 0.f, 0.f, 0.f};
    #pragma unroll
    for (int dt = 0; dt < 2; dt++) {
      f32x4 s0 = __builtin_amdgcn_mfma_f32_16x16x32_bf16(kf0, qf[dt], z, 0, 0, 0);
      f32x4 s1 = __builtin_amdgcn_mfma_f32_16x16x32_bf16(kf1, qf[dt], z, 0, 0, 0);
      float p0 = fexp2(s0[0]), p1 = fexp2(s0[1]), p2 = fexp2(s0[2]), p3 = fexp2(s0[3]);
      float p4 = fexp2(s1[0]), p5 = fexp2(s1[1]), p6 = fexp2(s1[2]), p7 = fexp2(s1[3]);
      // sigma: k=g*8+{0..3} -> e=4g+{0..3}; k=g*8+{4..7} -> e=16+4g+{0..3}
      uint4 pu = {pk(p0, p1), pk(p2, p3), pk(p4, p5), pk(p6, p7)};
      bf16x8 pf = as_bf(pu);
      lacc[dt] = __builtin_amdgcn_mfma_f32_16x16x32_bf16(ones, pf, lacc[dt], 0, 0, 0);
      O[dt][0] = __builtin_amdgcn_mfma_f32_16x16x32_bf16(vf0, pf, O[dt][0], 0, 0, 0);
      O[dt][1] = __builtin_amdgcn_mfma_f32_16x16x32_bf16(vf1, pf, O[dt][1], 0, 0, 0);
    }
    __syncthreads();
  }

  // ---- split-K merge with partner wave (w ^ 4); wave writes channel half ct=grp ----
  // (Ks/Vs dead from here; OP aliases them — the barrier above separates phases)
  #pragma unroll
  for (int dt = 0; dt < 2; dt++) {
    #pragma unroll
    for (int ct = 0; ct < 2; ct++)
      #pragma unroll
      for (int r = 0; r < 4; r++) sm.OP[wv][lane][dt * 8 + ct * 4 + r] = O[dt][ct][r];
    sm.OP[wv][lane][16 + dt] = lacc[dt][0];
  }
  __syncthreads();
  const int pw = wv ^ 4;
  #pragma unroll
  for (int dt = 0; dt < 2; dt++) {
    const float inv = 1.0f / (lacc[dt][0] + sm.OP[pw][lane][16 + dt]);
    const int d = d0 + dt * 16 + li;
    #pragma unroll
    for (int r = 0; r < 4; r++) {
      float val = O[dt][grp][r] + sm.OP[pw][lane][dt * 8 + grp * 4 + r];
      qp[(size_t)(grp * 16 + g * 4 + r) * HW + d] = f2bf_r(val * inv);
    }
  }
}

// ---------------- MFMA GEMM proj + bias + bf16 residual, fp32 out ----------------
__global__ __launch_bounds__(256) void proj_gemm(
    const ushort* __restrict__ qkvb, const float* __restrict__ w,
    const float* __restrict__ bias, const ushort* __restrict__ xnb, float* __restrict__ out) {
  const int b = blockIdx.z, m0 = blockIdx.y * 64, n0 = blockIdx.x * 64;
  const int tid = threadIdx.x, lane = tid & 63, wv = tid >> 6;
  const int li = lane & 15, g = lane >> 4;
  __shared__ ushort Ws[64][GP];
  __shared__ ushort Xs[64][GP];

  {
    const int row = tid >> 2, c0 = (tid & 3) * 32;
    const float* wr = w + (size_t)(m0 + row) * C + c0;
    #pragma unroll
    for (int k = 0; k < 4; k++) {
      float4 f0 = ((const float4*)wr)[k * 2];
      float4 f1 = ((const float4*)wr)[k * 2 + 1];
      uint4 u = {pk(f0.x, f0.y), pk(f0.z, f0.w), pk(f1.x, f1.y), pk(f1.z, f1.w)};
      *(uint4*)&Ws[row][c0 + k * 8] = u;
    }
  }
  {
    const int nX = tid & 63, c0 = (tid >> 6) * 32;
    const ushort* xb = qkvb + (size_t)(b * 3 * C + c0) * HW + n0 + nX;
    #pragma unroll
    for (int k = 0; k < 4; k++) {
      ushort t8[8];
      #pragma unroll
      for (int j = 0; j < 8; j++) t8[j] = xb[(size_t)(k * 8 + j) * HW];
      uint4 u;
      u.x = t8[0] | ((uint)t8[1] << 16);
      u.y = t8[2] | ((uint)t8[3] << 16);
      u.z = t8[4] | ((uint)t8[5] << 16);
      u.w = t8[6] | ((uint)t8[7] << 16);
      *(uint4*)&Xs[nX][c0 + k * 8] = u;
    }
  }
  __syncthreads();

  f32x4 acc[4];
  #pragma unroll
  for (int nt = 0; nt < 4; nt++) acc[nt] = (f32x4){0.f, 0.f, 0.f, 0.f};
  #pragma unroll
  for (int kk = 0; kk < 4; kk++) {
    bf16x8 af = *(const bf16x8*)&Ws[wv * 16 + li][kk * 32 + g * 8];
    #pragma unroll
    for (int nt = 0; nt < 4; nt++) {
      bf16x8 bfr = *(const bf16x8*)&Xs[nt * 16 + li][kk * 32 + g * 8];
      acc[nt] = __builtin_amdgcn_mfma_f32_16x16x32_bf16(af, bfr, acc[nt], 0, 0, 0);
    }
  }
  const int ob = m0 + wv * 16 + g * 4;
  #pragma unroll
  for (int r = 0; r < 4; r++) {
    float bi = bias[ob + r];
    #pragma unroll
    for (int nt = 0; nt < 4; nt++) {
      size_t idx = (size_t)(b * C + ob + r) * HW + n0 + nt * 16 + li;
      out[idx] = acc[nt][r] + bi + bf2f(xnb[idx]);
    }
  }
}

extern "C" void kernel_launch(void* const* d_in, const int* in_sizes, int n_in,
                              void* d_out, int out_size, void* d_ws, size_t ws_size,
                              hipStream_t stream) {
  const float* x     = (const float*)d_in[0];
  const float* gn_w  = (const float*)d_in[1];
  const float* gn_b  = (const float*)d_in[2];
  const float* qkv_w = (const float*)d_in[3];
  const float* qkv_b = (const float*)d_in[4];
  const float* pw    = (const float*)d_in[5];
  const float* pb    = (const float*)d_in[6];
  float* out = (float*)d_out;

  float*  stats = (float*)d_ws;                              // 512 floats (pad to 4 KB)
  ushort* xnb   = (ushort*)((char*)d_ws + 4096);             // 4 MB  bf16 [b][c][hw]
  ushort* qkvb  = xnb + (size_t)BATCH * C * HW;              // 12 MB bf16
  ushort* kt    = qkvb + (size_t)BATCH * 3 * C * HW;         // 4 MB  [bh][e][c]

  gn_part<<<dim3(256), dim3(256), 0, stream>>>(x, stats);
  gn_apply<<<dim3(C, BATCH), dim3(256), 0, stream>>>(x, gn_w, gn_b, stats, xnb);
  qkv_gemm<<<dim3(HW / 64, 6, BATCH), dim3(256), 0, stream>>>(xnb, qkv_w, qkv_b, qkvb);
  kvprep_kernel<<<dim3(HW / 64, BATCH * NH), dim3(256), 0, stream>>>(qkvb, kt);
  attn_kernel<<<dim3(HW / 128, BATCH * NH), dim3(512), 0, stream>>>(qkvb, kt);
  proj_gemm<<<dim3(HW / 64, 2, BATCH), dim3(256), 0, stream>>>(qkvb, pw, pb, xnb, out);
}

// Round 11
// 162.112 us; speedup vs baseline: 1.0543x; 1.0199x over previous
//
#include <hip/hip_runtime.h>
#include <math.h>

#define BATCH 4
#define C 128
#define HW 4096
#define G 8
#define CPG 16
#define NH 4
#define HD 32
#define EPS 1e-5f
#define SCALE 0.08838834764831845f   // 128^-0.5
#define LOG2E 1.44269504088896340f
#define KP 40                         // attn K/V LDS pitch (ushorts), r8-proven
#define GP 136                        // gemm LDS pitch (ushorts): 16B-aligned rows

typedef unsigned int uint;
typedef unsigned short ushort;
typedef __attribute__((ext_vector_type(8))) short bf16x8;   // 8 bf16 (4 VGPRs)
typedef __attribute__((ext_vector_type(4))) float f32x4;

__device__ __forceinline__ ushort f2bf(float x) {
  uint u = __float_as_uint(x);
  u += 0x7fff + ((u >> 16) & 1);   // RNE
  return (ushort)(u >> 16);
}
__device__ __forceinline__ ushort f2bf_r(float x) {   // round-half-away, 2 insts
  return (ushort)((__float_as_uint(x) + 0x8000u) >> 16);
}
__device__ __forceinline__ float bf2f(ushort h) {
  return __uint_as_float(((uint)h) << 16);
}
// pack two f32 -> bf16 pair (a low). gfx950: single v_cvt_pk_bf16_f32.
__device__ __forceinline__ uint pk(float a, float b) {
#if __has_builtin(__builtin_amdgcn_cvt_pk_bf16_f32)
  auto r = __builtin_amdgcn_cvt_pk_bf16_f32(a, b);
  union { decltype(r) v; uint u; } x;
  x.v = r;
  return x.u;
#else
  uint ua = __float_as_uint(a) + 0x8000u;
  uint ub = __float_as_uint(b) + 0x8000u;
  return __builtin_amdgcn_perm(ub, ua, 0x07060302);
#endif
}
__device__ __forceinline__ bf16x8 as_bf(uint4 u) {
  union { uint4 a; bf16x8 b; } x; x.a = u; return x.b;
}
__device__ __forceinline__ float fexp2(float x) {
#if __has_builtin(__builtin_amdgcn_exp2f)
  return __builtin_amdgcn_exp2f(x);   // raw v_exp_f32
#else
  return __exp2f(x);
#endif
}

// ---------------- GN pass 1: deterministic partials, plain stores ----------------
__global__ __launch_bounds__(256) void gn_part(
    const float* __restrict__ x, float* __restrict__ stats) {
  const int bg = blockIdx.x >> 3, chunk = blockIdx.x & 7;
  const float* xp = x + (size_t)bg * (CPG * HW) + chunk * 8192;
  const int tid = threadIdx.x;
  float s = 0.f, ss = 0.f;
  #pragma unroll
  for (int j = 0; j < 8; j++) {
    float4 v = ((const float4*)xp)[j * 256 + tid];
    s += (v.x + v.y) + (v.z + v.w);
    ss += (v.x * v.x + v.y * v.y) + (v.z * v.z + v.w * v.w);
  }
  #pragma unroll
  for (int off = 32; off; off >>= 1) {
    s  += __shfl_down(s, off);
    ss += __shfl_down(ss, off);
  }
  __shared__ float rs[4], rss[4];
  const int lane = tid & 63, wid = tid >> 6;
  if (lane == 0) { rs[wid] = s; rss[wid] = ss; }
  __syncthreads();
  if (tid == 0) {
    stats[(bg * 8 + chunk) * 2]     = (rs[0] + rs[1]) + (rs[2] + rs[3]);
    stats[(bg * 8 + chunk) * 2 + 1] = (rss[0] + rss[1]) + (rss[2] + rss[3]);
  }
}

// helper: (ca, cb) for channel c of batch from stats
__device__ __forceinline__ void gn_coeff(
    const float* __restrict__ stats, const float* __restrict__ w,
    const float* __restrict__ b, int batch, int c, float& ca, float& cb) {
  const int bg = batch * G + (c >> 4);
  float s = 0.f, ss = 0.f;
  #pragma unroll
  for (int k = 0; k < 8; k++) {
    s  += stats[(bg * 8 + k) * 2];
    ss += stats[(bg * 8 + k) * 2 + 1];
  }
  const float mean = s * (1.0f / 65536.0f);
  const float var  = ss * (1.0f / 65536.0f) - mean * mean;
  const float inv  = rsqrtf(var + EPS);
  ca = w[c] * inv;
  cb = b[c] - mean * ca;
}

// ---------------- MFMA GEMM with fused GroupNorm: qkv = W @ gn(x) ----------------
// single-stage full-K panels (64x128), X staged directly from fp32 x with
// on-the-fly normalize (CA/CB per channel from stats in LDS)
__global__ __launch_bounds__(256) void qkv_gemm(
    const float* __restrict__ x, const float* __restrict__ stats,
    const float* __restrict__ gnw, const float* __restrict__ gnb,
    const float* __restrict__ w, const float* __restrict__ bias,
    ushort* __restrict__ qkvb) {
  const int b = blockIdx.z, m0 = blockIdx.y * 64, n0 = blockIdx.x * 64;
  const int tid = threadIdx.x, lane = tid & 63, wv = tid >> 6;
  const int li = lane & 15, g = lane >> 4;
  __shared__ ushort Ws[64][GP];
  __shared__ ushort Xs[64][GP];
  __shared__ float CA[C], CB[C];

  if (tid < C) gn_coeff(stats, gnw, gnb, b, tid, CA[tid], CB[tid]);
  __syncthreads();

  // stage W: thread -> (row, 32-col chunk); fp32->bf16
  {
    const int row = tid >> 2, c0 = (tid & 3) * 32;
    const float* wr = w + (size_t)(m0 + row) * C + c0;
    #pragma unroll
    for (int k = 0; k < 4; k++) {
      float4 f0 = ((const float4*)wr)[k * 2];
      float4 f1 = ((const float4*)wr)[k * 2 + 1];
      uint4 u = {pk(f0.x, f0.y), pk(f0.z, f0.w), pk(f1.x, f1.y), pk(f1.z, f1.w)};
      *(uint4*)&Ws[row][c0 + k * 8] = u;
    }
  }
  // stage X transposed with fused GN: Xs[n][c] = bf16(x*ca + cb)
  {
    const int nX = tid & 63, c0 = (tid >> 6) * 32;
    const float* xb = x + (size_t)(b * C + c0) * HW + n0 + nX;
    #pragma unroll
    for (int k = 0; k < 4; k++) {
      float xv[8];
      #pragma unroll
      for (int j = 0; j < 8; j++) {
        int c = c0 + k * 8 + j;
        xv[j] = fmaf(xb[(size_t)(k * 8 + j) * HW], CA[c], CB[c]);
      }
      uint4 u = {pk(xv[0], xv[1]), pk(xv[2], xv[3]), pk(xv[4], xv[5]), pk(xv[6], xv[7])};
      *(uint4*)&Xs[nX][c0 + k * 8] = u;
    }
  }
  __syncthreads();

  f32x4 acc[4];
  #pragma unroll
  for (int nt = 0; nt < 4; nt++) acc[nt] = (f32x4){0.f, 0.f, 0.f, 0.f};
  #pragma unroll
  for (int kk = 0; kk < 4; kk++) {
    bf16x8 af = *(const bf16x8*)&Ws[wv * 16 + li][kk * 32 + g * 8];
    #pragma unroll
    for (int nt = 0; nt < 4; nt++) {
      bf16x8 bfr = *(const bf16x8*)&Xs[nt * 16 + li][kk * 32 + g * 8];
      acc[nt] = __builtin_amdgcn_mfma_f32_16x16x32_bf16(af, bfr, acc[nt], 0, 0, 0);
    }
  }
  const int ob = m0 + wv * 16 + g * 4;
  #pragma unroll
  for (int r = 0; r < 4; r++) {
    float bi = bias[ob + r];
    #pragma unroll
    for (int nt = 0; nt < 4; nt++) {
      qkvb[(size_t)(b * 3 * C + ob + r) * HW + n0 + nt * 16 + li] = f2bf(acc[nt][r] + bi);
    }
  }
}

// ---------------- K prep: KT[bh][e][c] (c contiguous), vectorized ----------------
__global__ __launch_bounds__(256) void kvprep_kernel(
    const ushort* __restrict__ qkvb, ushort* __restrict__ kt) {
  const int bh = blockIdx.y, b = bh >> 2, h = bh & 3;
  const int e0 = blockIdx.x * 64;
  const ushort* kp = qkvb + (size_t)(b * 3 * C + C + h * HD) * HW;
  ushort* ktp = kt + (size_t)bh * HW * HD;
  const int t = threadIdx.x;

  __shared__ ushort Kt[32][66];
  {
    const int c = t >> 3, e8 = (t & 7) * 8;
    *(uint4*)&Kt[c][e8] = *(const uint4*)&kp[(size_t)c * HW + e0 + e8];
  }
  __syncthreads();
  {
    const int e = t >> 2, c0 = (t & 3) * 8;
    ushort o[8];
    #pragma unroll
    for (int j = 0; j < 8; j++) o[j] = Kt[c0 + j][e];
    uint4 u;
    u.x = o[0] | ((uint)o[1] << 16);
    u.y = o[2] | ((uint)o[3] << 16);
    u.z = o[4] | ((uint)o[5] << 16);
    u.w = o[6] | ((uint)o[7] << 16);
    *(uint4*)&ktp[(size_t)(e0 + e) * HD + c0] = u;
  }
}

// ---------------- MFMA flash attention: r8 body + OP/tile LDS union ----------------
// __launch_bounds__(512,4): 128-reg budget, r8 codegen (52 VGPR, no spill).
__global__ __launch_bounds__(512, 4) void attn_kernel(
    ushort* __restrict__ qkv, const ushort* __restrict__ kt) {
  const int bh = blockIdx.y, b = bh >> 2, h = bh & 3;
  const int tid = threadIdx.x, lane = tid & 63, wv = tid >> 6;
  const int li = lane & 15, g = lane >> 4;
  const int grp = wv >> 2, w4 = wv & 3;
  ushort* qp = qkv + (size_t)(b * 3 * C + h * HD) * HW;
  const ushort* vpl = qkv + (size_t)(b * 3 * C + 2 * C + h * HD) * HW;
  const ushort* ktp = kt + (size_t)bh * HW * HD;
  const int d0 = blockIdx.x * 128 + w4 * 32;

  struct SmemT {
    union {
      struct { ushort Ks[2][2][32][KP]; ushort Vs[2][2][32][KP]; } t;  // 20480 B
      float OP[8][64][19];                                             // 38912 B
    };
  };
  __shared__ SmemT sm;

  // Q B-fragments (2 d-tiles), prescaled by SCALE*log2(e)
  const float qs = SCALE * LOG2E;
  bf16x8 qf[2];
  #pragma unroll
  for (int dt = 0; dt < 2; dt++) {
    int d = d0 + dt * 16 + li;
    float qv[8];
    #pragma unroll
    for (int j = 0; j < 8; j++)
      qv[j] = bf2f(qp[(size_t)(g * 8 + j) * HW + d]) * qs;
    uint4 qu = {pk(qv[0], qv[1]), pk(qv[2], qv[3]), pk(qv[4], qv[5]), pk(qv[6], qv[7])};
    qf[dt] = as_bf(qu);
  }

  f32x4 O[2][2];
  #pragma unroll
  for (int dt = 0; dt < 2; dt++)
    #pragma unroll
    for (int ct = 0; ct < 2; ct++) O[dt][ct] = (f32x4){0.f, 0.f, 0.f, 0.f};
  f32x4 lacc[2] = {(f32x4){0.f, 0.f, 0.f, 0.f}, (f32x4){0.f, 0.f, 0.f, 0.f}};
  const uint one2 = 0x3F803F80u;
  const bf16x8 ones = as_bf((uint4){one2, one2, one2, one2});

  // staging: group-local threads 0..127 stage K, 128..255 stage V
  const int gt = tid & 255;
  const bool isK = gt < 128;
  const int t2 = gt & 127;
  const int srow = t2 >> 2, scol8 = (t2 & 3) * 8;
  const ushort* gK = ktp + (size_t)(grp * 64) * 1024 + t2 * 8;       // + n*1024
  const ushort* gV = vpl + (size_t)srow * HW + grp * 2048 + scol8;   // + n*32

  uint4 st = isK ? *(const uint4*)&gK[0] : *(const uint4*)&gV[0];
  if (isK) *(uint4*)&sm.t.Ks[grp][0][srow][scol8] = st;
  else     *(uint4*)&sm.t.Vs[grp][0][srow][scol8] = st;
  st = isK ? *(const uint4*)&gK[1024] : *(const uint4*)&gV[32];
  __syncthreads();

  for (int it = 0; it < 64; it++) {
    const int cur = it & 1, nxt = cur ^ 1;
    // store tile it+1 (loaded last iter) into the other buffer
    if (isK) *(uint4*)&sm.t.Ks[grp][nxt][srow][scol8] = st;
    else     *(uint4*)&sm.t.Vs[grp][nxt][srow][scol8] = st;

    // fragments from current buffer
    bf16x8 kf0 = *(const bf16x8*)&sm.t.Ks[grp][cur][li][g * 8];
    bf16x8 kf1 = *(const bf16x8*)&sm.t.Ks[grp][cur][16 + li][g * 8];
    uint2 va0 = *(const uint2*)&sm.t.Vs[grp][cur][li][4 * g];
    uint2 va1 = *(const uint2*)&sm.t.Vs[grp][cur][li][16 + 4 * g];
    uint2 vb0 = *(const uint2*)&sm.t.Vs[grp][cur][16 + li][4 * g];
    uint2 vb1 = *(const uint2*)&sm.t.Vs[grp][cur][16 + li][16 + 4 * g];
    bf16x8 vf0 = as_bf((uint4){va0.x, va0.y, va1.x, va1.y});
    bf16x8 vf1 = as_bf((uint4){vb0.x, vb0.y, vb1.x, vb1.y});

    // prefetch tile it+2 into regs (wraps in-range on last iters: dead data)
    const int tn = (it + 2) & 63;
    st = isK ? *(const uint4*)&gK[(size_t)tn * 1024] : *(const uint4*)&gV[tn * 32];

    const f32x4 z = (f32x4){0.f, 0.f, 0.f, 0.f};
    #pragma unroll
    for (int dt = 0; dt < 2; dt++) {
      f32x4 s0 = __builtin_amdgcn_mfma_f32_16x16x32_bf16(kf0, qf[dt], z, 0, 0, 0);
      f32x4 s1 = __builtin_amdgcn_mfma_f32_16x16x32_bf16(kf1, qf[dt], z, 0, 0, 0);
      float p0 = fexp2(s0[0]), p1 = fexp2(s0[1]), p2 = fexp2(s0[2]), p3 = fexp2(s0[3]);
      float p4 = fexp2(s1[0]), p5 = fexp2(s1[1]), p6 = fexp2(s1[2]), p7 = fexp2(s1[3]);
      // sigma: k=g*8+{0..3} -> e=4g+{0..3}; k=g*8+{4..7} -> e=16+4g+{0..3}
      uint4 pu = {pk(p0, p1), pk(p2, p3), pk(p4, p5), pk(p6, p7)};
      bf16x8 pf = as_bf(pu);
      lacc[dt] = __builtin_amdgcn_mfma_f32_16x16x32_bf16(ones, pf, lacc[dt], 0, 0, 0);
      O[dt][0] = __builtin_amdgcn_mfma_f32_16x16x32_bf16(vf0, pf, O[dt][0], 0, 0, 0);
      O[dt][1] = __builtin_amdgcn_mfma_f32_16x16x32_bf16(vf1, pf, O[dt][1], 0, 0, 0);
    }
    __syncthreads();
  }

  // ---- split-K merge with partner wave (w ^ 4); wave writes channel half ct=grp ----
  #pragma unroll
  for (int dt = 0; dt < 2; dt++) {
    #pragma unroll
    for (int ct = 0; ct < 2; ct++)
      #pragma unroll
      for (int r = 0; r < 4; r++) sm.OP[wv][lane][dt * 8 + ct * 4 + r] = O[dt][ct][r];
    sm.OP[wv][lane][16 + dt] = lacc[dt][0];
  }
  __syncthreads();
  const int pw = wv ^ 4;
  #pragma unroll
  for (int dt = 0; dt < 2; dt++) {
    const float inv = 1.0f / (lacc[dt][0] + sm.OP[pw][lane][16 + dt]);
    const int d = d0 + dt * 16 + li;
    #pragma unroll
    for (int r = 0; r < 4; r++) {
      float val = O[dt][grp][r] + sm.OP[pw][lane][dt * 8 + grp * 4 + r];
      qp[(size_t)(grp * 16 + g * 4 + r) * HW + d] = f2bf_r(val * inv);
    }
  }
}

// ---------------- MFMA GEMM proj + bias + fp32 GN residual, fp32 out ----------------
__global__ __launch_bounds__(256) void proj_gemm(
    const ushort* __restrict__ qkvb, const float* __restrict__ w,
    const float* __restrict__ bias, const float* __restrict__ x,
    const float* __restrict__ stats, const float* __restrict__ gnw,
    const float* __restrict__ gnb, float* __restrict__ out) {
  const int b = blockIdx.z, m0 = blockIdx.y * 64, n0 = blockIdx.x * 64;
  const int tid = threadIdx.x, lane = tid & 63, wv = tid >> 6;
  const int li = lane & 15, g = lane >> 4;
  __shared__ ushort Ws[64][GP];
  __shared__ ushort Xs[64][GP];
  __shared__ float CA[64], CB[64];

  if (tid < 64) gn_coeff(stats, gnw, gnb, b, m0 + tid, CA[tid], CB[tid]);

  {
    const int row = tid >> 2, c0 = (tid & 3) * 32;
    const float* wr = w + (size_t)(m0 + row) * C + c0;
    #pragma unroll
    for (int k = 0; k < 4; k++) {
      float4 f0 = ((const float4*)wr)[k * 2];
      float4 f1 = ((const float4*)wr)[k * 2 + 1];
      uint4 u = {pk(f0.x, f0.y), pk(f0.z, f0.w), pk(f1.x, f1.y), pk(f1.z, f1.w)};
      *(uint4*)&Ws[row][c0 + k * 8] = u;
    }
  }
  {
    const int nX = tid & 63, c0 = (tid >> 6) * 32;
    const ushort* xb = qkvb + (size_t)(b * 3 * C + c0) * HW + n0 + nX;
    #pragma unroll
    for (int k = 0; k < 4; k++) {
      ushort t8[8];
      #pragma unroll
      for (int j = 0; j < 8; j++) t8[j] = xb[(size_t)(k * 8 + j) * HW];
      uint4 u;
      u.x = t8[0] | ((uint)t8[1] << 16);
      u.y = t8[2] | ((uint)t8[3] << 16);
      u.z = t8[4] | ((uint)t8[5] << 16);
      u.w = t8[6] | ((uint)t8[7] << 16);
      *(uint4*)&Xs[nX][c0 + k * 8] = u;
    }
  }
  __syncthreads();

  f32x4 acc[4];
  #pragma unroll
  for (int nt = 0; nt < 4; nt++) acc[nt] = (f32x4){0.f, 0.f, 0.f, 0.f};
  #pragma unroll
  for (int kk = 0; kk < 4; kk++) {
    bf16x8 af = *(const bf16x8*)&Ws[wv * 16 + li][kk * 32 + g * 8];
    #pragma unroll
    for (int nt = 0; nt < 4; nt++) {
      bf16x8 bfr = *(const bf16x8*)&Xs[nt * 16 + li][kk * 32 + g * 8];
      acc[nt] = __builtin_amdgcn_mfma_f32_16x16x32_bf16(af, bfr, acc[nt], 0, 0, 0);
    }
  }
  const int ob = m0 + wv * 16 + g * 4;
  #pragma unroll
  for (int r = 0; r < 4; r++) {
    const float bi = bias[ob + r];
    const float ca = CA[wv * 16 + g * 4 + r], cb = CB[wv * 16 + g * 4 + r];
    #pragma unroll
    for (int nt = 0; nt < 4; nt++) {
      size_t idx = (size_t)(b * C + ob + r) * HW + n0 + nt * 16 + li;
      out[idx] = acc[nt][r] + bi + fmaf(x[idx], ca, cb);
    }
  }
}

extern "C" void kernel_launch(void* const* d_in, const int* in_sizes, int n_in,
                              void* d_out, int out_size, void* d_ws, size_t ws_size,
                              hipStream_t stream) {
  const float* x     = (const float*)d_in[0];
  const float* gn_w  = (const float*)d_in[1];
  const float* gn_b  = (const float*)d_in[2];
  const float* qkv_w = (const float*)d_in[3];
  const float* qkv_b = (const float*)d_in[4];
  const float* pw    = (const float*)d_in[5];
  const float* pb    = (const float*)d_in[6];
  float* out = (float*)d_out;

  float*  stats = (float*)d_ws;                              // 512 floats (pad to 4 KB)
  ushort* qkvb  = (ushort*)((char*)d_ws + 4096);             // 12 MB bf16
  ushort* kt    = qkvb + (size_t)BATCH * 3 * C * HW;         // 4 MB  [bh][e][c]

  gn_part<<<dim3(256), dim3(256), 0, stream>>>(x, stats);
  qkv_gemm<<<dim3(HW / 64, 6, BATCH), dim3(256), 0, stream>>>(
      x, stats, gn_w, gn_b, qkv_w, qkv_b, qkvb);
  kvprep_kernel<<<dim3(HW / 64, BATCH * NH), dim3(256), 0, stream>>>(qkvb, kt);
  attn_kernel<<<dim3(HW / 128, BATCH * NH), dim3(512), 0, stream>>>(qkvb, kt);
  proj_gemm<<<dim3(HW / 64, 2, BATCH), dim3(256), 0, stream>>>(
      qkvb, pw, pb, x, stats, gn_w, gn_b, out);
}

// Round 12
// 144.436 us; speedup vs baseline: 1.1833x; 1.1224x over previous
//
#include <hip/hip_runtime.h>
#include <math.h>

#define BATCH 4
#define C 128
#define HW 4096
#define G 8
#define CPG 16
#define NH 4
#define HD 32
#define EPS 1e-5f
#define SCALE 0.08838834764831845f   // 128^-0.5
#define LOG2E 1.44269504088896340f
#define GP 136                        // gemm LDS pitch (ushorts): 16B-aligned rows

typedef unsigned int uint;
typedef unsigned short ushort;
typedef __attribute__((ext_vector_type(8))) short bf16x8;   // 8 bf16 (4 VGPRs)
typedef __attribute__((ext_vector_type(4))) float f32x4;

__device__ __forceinline__ ushort f2bf(float x) {
  uint u = __float_as_uint(x);
  u += 0x7fff + ((u >> 16) & 1);   // RNE
  return (ushort)(u >> 16);
}
__device__ __forceinline__ ushort f2bf_r(float x) {   // round-half-away, 2 insts
  return (ushort)((__float_as_uint(x) + 0x8000u) >> 16);
}
__device__ __forceinline__ float bf2f(ushort h) {
  return __uint_as_float(((uint)h) << 16);
}
// pack two f32 -> bf16 pair (a low). gfx950: single v_cvt_pk_bf16_f32.
__device__ __forceinline__ uint pk(float a, float b) {
#if __has_builtin(__builtin_amdgcn_cvt_pk_bf16_f32)
  auto r = __builtin_amdgcn_cvt_pk_bf16_f32(a, b);
  union { decltype(r) v; uint u; } x;
  x.v = r;
  return x.u;
#else
  uint ua = __float_as_uint(a) + 0x8000u;
  uint ub = __float_as_uint(b) + 0x8000u;
  return __builtin_amdgcn_perm(ub, ua, 0x07060302);
#endif
}
__device__ __forceinline__ bf16x8 as_bf(uint4 u) {
  union { uint4 a; bf16x8 b; } x; x.a = u; return x.b;
}
__device__ __forceinline__ float fexp2(float x) {
#if __has_builtin(__builtin_amdgcn_exp2f)
  return __builtin_amdgcn_exp2f(x);   // raw v_exp_f32
#else
  return __exp2f(x);
#endif
}

// ---------------- GN pass 1: deterministic partials, plain stores ----------------
__global__ __launch_bounds__(256) void gn_part(
    const float* __restrict__ x, float* __restrict__ stats) {
  const int bg = blockIdx.x >> 3, chunk = blockIdx.x & 7;
  const float* xp = x + (size_t)bg * (CPG * HW) + chunk * 8192;
  const int tid = threadIdx.x;
  float s = 0.f, ss = 0.f;
  #pragma unroll
  for (int j = 0; j < 8; j++) {
    float4 v = ((const float4*)xp)[j * 256 + tid];
    s += (v.x + v.y) + (v.z + v.w);
    ss += (v.x * v.x + v.y * v.y) + (v.z * v.z + v.w * v.w);
  }
  #pragma unroll
  for (int off = 32; off; off >>= 1) {
    s  += __shfl_down(s, off);
    ss += __shfl_down(ss, off);
  }
  __shared__ float rs[4], rss[4];
  const int lane = tid & 63, wid = tid >> 6;
  if (lane == 0) { rs[wid] = s; rss[wid] = ss; }
  __syncthreads();
  if (tid == 0) {
    stats[(bg * 8 + chunk) * 2]     = (rs[0] + rs[1]) + (rs[2] + rs[3]);
    stats[(bg * 8 + chunk) * 2 + 1] = (rss[0] + rss[1]) + (rss[2] + rss[3]);
  }
}

// helper: (ca, cb) for channel c of batch from stats
__device__ __forceinline__ void gn_coeff(
    const float* __restrict__ stats, const float* __restrict__ w,
    const float* __restrict__ b, int batch, int c, float& ca, float& cb) {
  const int bg = batch * G + (c >> 4);
  float s = 0.f, ss = 0.f;
  #pragma unroll
  for (int k = 0; k < 8; k++) {
    s  += stats[(bg * 8 + k) * 2];
    ss += stats[(bg * 8 + k) * 2 + 1];
  }
  const float mean = s * (1.0f / 65536.0f);
  const float var  = ss * (1.0f / 65536.0f) - mean * mean;
  const float inv  = rsqrtf(var + EPS);
  ca = w[c] * inv;
  cb = b[c] - mean * ca;
}

// ---------------- MFMA GEMM with fused GroupNorm: qkv = W @ gn(x) ----------------
// K channels (blockIdx.y 2,3) are written directly into the transposed
// kt[bh][e][c] layout (kvprep kernel eliminated); Q/V channels to qkvb.
__global__ __launch_bounds__(256) void qkv_gemm(
    const float* __restrict__ x, const float* __restrict__ stats,
    const float* __restrict__ gnw, const float* __restrict__ gnb,
    const float* __restrict__ w, const float* __restrict__ bias,
    ushort* __restrict__ qkvb, ushort* __restrict__ kt) {
  const int b = blockIdx.z, m0 = blockIdx.y * 64, n0 = blockIdx.x * 64;
  const int tid = threadIdx.x, lane = tid & 63, wv = tid >> 6;
  const int li = lane & 15, g = lane >> 4;
  __shared__ ushort Ws[64][GP];
  __shared__ ushort Xs[64][GP];
  __shared__ float CA[C], CB[C];

  if (tid < C) gn_coeff(stats, gnw, gnb, b, tid, CA[tid], CB[tid]);
  __syncthreads();

  // stage W: thread -> (row, 32-col chunk); fp32->bf16
  {
    const int row = tid >> 2, c0 = (tid & 3) * 32;
    const float* wr = w + (size_t)(m0 + row) * C + c0;
    #pragma unroll
    for (int k = 0; k < 4; k++) {
      float4 f0 = ((const float4*)wr)[k * 2];
      float4 f1 = ((const float4*)wr)[k * 2 + 1];
      uint4 u = {pk(f0.x, f0.y), pk(f0.z, f0.w), pk(f1.x, f1.y), pk(f1.z, f1.w)};
      *(uint4*)&Ws[row][c0 + k * 8] = u;
    }
  }
  // stage X transposed with fused GN: Xs[n][c] = bf16(x*ca + cb)
  {
    const int nX = tid & 63, c0 = (tid >> 6) * 32;
    const float* xb = x + (size_t)(b * C + c0) * HW + n0 + nX;
    #pragma unroll
    for (int k = 0; k < 4; k++) {
      float xv[8];
      #pragma unroll
      for (int j = 0; j < 8; j++) {
        int c = c0 + k * 8 + j;
        xv[j] = fmaf(xb[(size_t)(k * 8 + j) * HW], CA[c], CB[c]);
      }
      uint4 u = {pk(xv[0], xv[1]), pk(xv[2], xv[3]), pk(xv[4], xv[5]), pk(xv[6], xv[7])};
      *(uint4*)&Xs[nX][c0 + k * 8] = u;
    }
  }
  __syncthreads();

  f32x4 acc[4];
  #pragma unroll
  for (int nt = 0; nt < 4; nt++) acc[nt] = (f32x4){0.f, 0.f, 0.f, 0.f};
  #pragma unroll
  for (int kk = 0; kk < 4; kk++) {
    bf16x8 af = *(const bf16x8*)&Ws[wv * 16 + li][kk * 32 + g * 8];
    #pragma unroll
    for (int nt = 0; nt < 4; nt++) {
      bf16x8 bfr = *(const bf16x8*)&Xs[nt * 16 + li][kk * 32 + g * 8];
      acc[nt] = __builtin_amdgcn_mfma_f32_16x16x32_bf16(af, bfr, acc[nt], 0, 0, 0);
    }
  }
  const int ob = m0 + wv * 16 + g * 4;
  if (blockIdx.y == 2 || blockIdx.y == 3) {
    // K channels: write transposed kt[b*NH+h][e][c_local]
    const int ck = ob - C;            // 0..127 within the K block
    const int h  = ck >> 5;
    const int cl = ck & 31;
    ushort* ktp = kt + (size_t)(b * NH + h) * HW * HD;
    #pragma unroll
    for (int r = 0; r < 4; r++) {
      float bi = bias[ob + r];
      #pragma unroll
      for (int nt = 0; nt < 4; nt++) {
        int e = n0 + nt * 16 + li;
        ktp[(size_t)e * HD + cl + r] = f2bf(acc[nt][r] + bi);
      }
    }
  } else {
    #pragma unroll
    for (int r = 0; r < 4; r++) {
      float bi = bias[ob + r];
      #pragma unroll
      for (int nt = 0; nt < 4; nt++) {
        qkvb[(size_t)(b * 3 * C + ob + r) * HW + n0 + nt * 16 + li] = f2bf(acc[nt][r] + bi);
      }
    }
  }
}

// ---------------- MFMA flash attention: r8-exact (separate LDS arrays) ----------------
// block = 8 waves x 32 q = 128 q. Wave-group A (waves 0-3) does keys 0..2047,
// group B (waves 4-7) keys 2048..4095; each group shares a double-buffered LDS
// K/V tile stream. Merge: partner-wave (w ^ 4) partial exchange via LDS.
// S^T = K^T Q; P stays in registers (sigma absorbed in V ds_read addressing).
__global__ __launch_bounds__(512, 4) void attn_kernel(
    ushort* __restrict__ qkv, const ushort* __restrict__ kt) {
  const int bh = blockIdx.y, b = bh >> 2, h = bh & 3;
  const int tid = threadIdx.x, lane = tid & 63, wv = tid >> 6;
  const int li = lane & 15, g = lane >> 4;
  const int grp = wv >> 2, w4 = wv & 3;
  ushort* qp = qkv + (size_t)(b * 3 * C + h * HD) * HW;
  const ushort* vpl = qkv + (size_t)(b * 3 * C + 2 * C + h * HD) * HW;
  const ushort* ktp = kt + (size_t)bh * HW * HD;
  const int d0 = blockIdx.x * 128 + w4 * 32;

  __shared__ ushort Ks[2][2][32][40];   // [grp][buf][e][c]
  __shared__ ushort Vs[2][2][32][40];   // [grp][buf][c][e]
  __shared__ float OP[8][64][19];       // merge: 16 O + 2 l, odd pitch

  // Q B-fragments (2 d-tiles), prescaled by SCALE*log2(e)
  const float qs = SCALE * LOG2E;
  bf16x8 qf[2];
  #pragma unroll
  for (int dt = 0; dt < 2; dt++) {
    int d = d0 + dt * 16 + li;
    float qv[8];
    #pragma unroll
    for (int j = 0; j < 8; j++)
      qv[j] = bf2f(qp[(size_t)(g * 8 + j) * HW + d]) * qs;
    uint4 qu = {pk(qv[0], qv[1]), pk(qv[2], qv[3]), pk(qv[4], qv[5]), pk(qv[6], qv[7])};
    qf[dt] = as_bf(qu);
  }

  f32x4 O[2][2];
  #pragma unroll
  for (int dt = 0; dt < 2; dt++)
    #pragma unroll
    for (int ct = 0; ct < 2; ct++) O[dt][ct] = (f32x4){0.f, 0.f, 0.f, 0.f};
  f32x4 lacc[2] = {(f32x4){0.f, 0.f, 0.f, 0.f}, (f32x4){0.f, 0.f, 0.f, 0.f}};
  const uint one2 = 0x3F803F80u;
  const bf16x8 ones = as_bf((uint4){one2, one2, one2, one2});

  // staging: group-local threads 0..127 stage K, 128..255 stage V
  const int gt = tid & 255;
  const bool isK = gt < 128;
  const int t2 = gt & 127;
  const int srow = t2 >> 2, scol8 = (t2 & 3) * 8;
  const ushort* gK = ktp + (size_t)(grp * 64) * 1024 + t2 * 8;       // + n*1024
  const ushort* gV = vpl + (size_t)srow * HW + grp * 2048 + scol8;   // + n*32

  uint4 st = isK ? *(const uint4*)&gK[0] : *(const uint4*)&gV[0];
  if (isK) *(uint4*)&Ks[grp][0][srow][scol8] = st;
  else     *(uint4*)&Vs[grp][0][srow][scol8] = st;
  st = isK ? *(const uint4*)&gK[1024] : *(const uint4*)&gV[32];
  __syncthreads();

  for (int it = 0; it < 64; it++) {
    const int cur = it & 1, nxt = cur ^ 1;
    // store tile it+1 (loaded last iter) into the other buffer
    if (isK) *(uint4*)&Ks[grp][nxt][srow][scol8] = st;
    else     *(uint4*)&Vs[grp][nxt][srow][scol8] = st;

    // fragments from current buffer
    bf16x8 kf0 = *(const bf16x8*)&Ks[grp][cur][li][g * 8];
    bf16x8 kf1 = *(const bf16x8*)&Ks[grp][cur][16 + li][g * 8];
    uint2 va0 = *(const uint2*)&Vs[grp][cur][li][4 * g];
    uint2 va1 = *(const uint2*)&Vs[grp][cur][li][16 + 4 * g];
    uint2 vb0 = *(const uint2*)&Vs[grp][cur][16 + li][4 * g];
    uint2 vb1 = *(const uint2*)&Vs[grp][cur][16 + li][16 + 4 * g];
    bf16x8 vf0 = as_bf((uint4){va0.x, va0.y, va1.x, va1.y});
    bf16x8 vf1 = as_bf((uint4){vb0.x, vb0.y, vb1.x, vb1.y});

    // prefetch tile it+2 into regs (wraps in-range on last iters: dead data)
    const int tn = (it + 2) & 63;
    st = isK ? *(const uint4*)&gK[(size_t)tn * 1024] : *(const uint4*)&gV[tn * 32];

    const f32x4 z = (f32x4){0.f, 0.f, 0.f, 0.f};
    #pragma unroll
    for (int dt = 0; dt < 2; dt++) {
      f32x4 s0 = __builtin_amdgcn_mfma_f32_16x16x32_bf16(kf0, qf[dt], z, 0, 0, 0);
      f32x4 s1 = __builtin_amdgcn_mfma_f32_16x16x32_bf16(kf1, qf[dt], z, 0, 0, 0);
      float p0 = fexp2(s0[0]), p1 = fexp2(s0[1]), p2 = fexp2(s0[2]), p3 = fexp2(s0[3]);
      float p4 = fexp2(s1[0]), p5 = fexp2(s1[1]), p6 = fexp2(s1[2]), p7 = fexp2(s1[3]);
      // sigma: k=g*8+{0..3} -> e=4g+{0..3}; k=g*8+{4..7} -> e=16+4g+{0..3}
      uint4 pu = {pk(p0, p1), pk(p2, p3), pk(p4, p5), pk(p6, p7)};
      bf16x8 pf = as_bf(pu);
      lacc[dt] = __builtin_amdgcn_mfma_f32_16x16x32_bf16(ones, pf, lacc[dt], 0, 0, 0);
      O[dt][0] = __builtin_amdgcn_mfma_f32_16x16x32_bf16(vf0, pf, O[dt][0], 0, 0, 0);
      O[dt][1] = __builtin_amdgcn_mfma_f32_16x16x32_bf16(vf1, pf, O[dt][1], 0, 0, 0);
    }
    __syncthreads();
  }

  // ---- split-K merge with partner wave (w ^ 4); wave writes channel half ct=grp ----
  #pragma unroll
  for (int dt = 0; dt < 2; dt++) {
    #pragma unroll
    for (int ct = 0; ct < 2; ct++)
      #pragma unroll
      for (int r = 0; r < 4; r++) OP[wv][lane][dt * 8 + ct * 4 + r] = O[dt][ct][r];
    OP[wv][lane][16 + dt] = lacc[dt][0];
  }
  __syncthreads();
  const int pw = wv ^ 4;
  #pragma unroll
  for (int dt = 0; dt < 2; dt++) {
    const float inv = 1.0f / (lacc[dt][0] + OP[pw][lane][16 + dt]);
    const int d = d0 + dt * 16 + li;
    #pragma unroll
    for (int r = 0; r < 4; r++) {
      float val = O[dt][grp][r] + OP[pw][lane][dt * 8 + grp * 4 + r];
      qp[(size_t)(grp * 16 + g * 4 + r) * HW + d] = f2bf_r(val * inv);
    }
  }
}

// ---------------- MFMA GEMM proj + bias + fp32 GN residual, fp32 out ----------------
__global__ __launch_bounds__(256) void proj_gemm(
    const ushort* __restrict__ qkvb, const float* __restrict__ w,
    const float* __restrict__ bias, const float* __restrict__ x,
    const float* __restrict__ stats, const float* __restrict__ gnw,
    const float* __restrict__ gnb, float* __restrict__ out) {
  const int b = blockIdx.z, m0 = blockIdx.y * 64, n0 = blockIdx.x * 64;
  const int tid = threadIdx.x, lane = tid & 63, wv = tid >> 6;
  const int li = lane & 15, g = lane >> 4;
  __shared__ ushort Ws[64][GP];
  __shared__ ushort Xs[64][GP];
  __shared__ float CA[64], CB[64];

  if (tid < 64) gn_coeff(stats, gnw, gnb, b, m0 + tid, CA[tid], CB[tid]);

  {
    const int row = tid >> 2, c0 = (tid & 3) * 32;
    const float* wr = w + (size_t)(m0 + row) * C + c0;
    #pragma unroll
    for (int k = 0; k < 4; k++) {
      float4 f0 = ((const float4*)wr)[k * 2];
      float4 f1 = ((const float4*)wr)[k * 2 + 1];
      uint4 u = {pk(f0.x, f0.y), pk(f0.z, f0.w), pk(f1.x, f1.y), pk(f1.z, f1.w)};
      *(uint4*)&Ws[row][c0 + k * 8] = u;
    }
  }
  {
    const int nX = tid & 63, c0 = (tid >> 6) * 32;
    const ushort* xb = qkvb + (size_t)(b * 3 * C + c0) * HW + n0 + nX;
    #pragma unroll
    for (int k = 0; k < 4; k++) {
      ushort t8[8];
      #pragma unroll
      for (int j = 0; j < 8; j++) t8[j] = xb[(size_t)(k * 8 + j) * HW];
      uint4 u;
      u.x = t8[0] | ((uint)t8[1] << 16);
      u.y = t8[2] | ((uint)t8[3] << 16);
      u.z = t8[4] | ((uint)t8[5] << 16);
      u.w = t8[6] | ((uint)t8[7] << 16);
      *(uint4*)&Xs[nX][c0 + k * 8] = u;
    }
  }
  __syncthreads();

  f32x4 acc[4];
  #pragma unroll
  for (int nt = 0; nt < 4; nt++) acc[nt] = (f32x4){0.f, 0.f, 0.f, 0.f};
  #pragma unroll
  for (int kk = 0; kk < 4; kk++) {
    bf16x8 af = *(const bf16x8*)&Ws[wv * 16 + li][kk * 32 + g * 8];
    #pragma unroll
    for (int nt = 0; nt < 4; nt++) {
      bf16x8 bfr = *(const bf16x8*)&Xs[nt * 16 + li][kk * 32 + g * 8];
      acc[nt] = __builtin_amdgcn_mfma_f32_16x16x32_bf16(af, bfr, acc[nt], 0, 0, 0);
    }
  }
  const int ob = m0 + wv * 16 + g * 4;
  #pragma unroll
  for (int r = 0; r < 4; r++) {
    const float bi = bias[ob + r];
    const float ca = CA[wv * 16 + g * 4 + r], cb = CB[wv * 16 + g * 4 + r];
    #pragma unroll
    for (int nt = 0; nt < 4; nt++) {
      size_t idx = (size_t)(b * C + ob + r) * HW + n0 + nt * 16 + li;
      out[idx] = acc[nt][r] + bi + fmaf(x[idx], ca, cb);
    }
  }
}

extern "C" void kernel_launch(void* const* d_in, const int* in_sizes, int n_in,
                              void* d_out, int out_size, void* d_ws, size_t ws_size,
                              hipStream_t stream) {
  const float* x     = (const float*)d_in[0];
  const float* gn_w  = (const float*)d_in[1];
  const float* gn_b  = (const float*)d_in[2];
  const float* qkv_w = (const float*)d_in[3];
  const float* qkv_b = (const float*)d_in[4];
  const float* pw    = (const float*)d_in[5];
  const float* pb    = (const float*)d_in[6];
  float* out = (float*)d_out;

  float*  stats = (float*)d_ws;                              // 512 floats (pad to 4 KB)
  ushort* qkvb  = (ushort*)((char*)d_ws + 4096);             // 12 MB bf16 (K-plane unused)
  ushort* kt    = qkvb + (size_t)BATCH * 3 * C * HW;         // 4 MB  [bh][e][c]

  gn_part<<<dim3(256), dim3(256), 0, stream>>>(x, stats);
  qkv_gemm<<<dim3(HW / 64, 6, BATCH), dim3(256), 0, stream>>>(
      x, stats, gn_w, gn_b, qkv_w, qkv_b, qkvb, kt);
  attn_kernel<<<dim3(HW / 128, BATCH * NH), dim3(512), 0, stream>>>(qkvb, kt);
  proj_gemm<<<dim3(HW / 64, 2, BATCH), dim3(256), 0, stream>>>(
      qkvb, pw, pb, x, stats, gn_w, gn_b, out);
}

// Round 13
// 142.019 us; speedup vs baseline: 1.2034x; 1.0170x over previous
//
#include <hip/hip_runtime.h>
#include <math.h>

#define BATCH 4
#define C 128
#define HW 4096
#define G 8
#define CPG 16
#define NH 4
#define HD 32
#define EPS 1e-5f
#define SCALE 0.08838834764831845f   // 128^-0.5
#define LOG2E 1.44269504088896340f
#define GP 136                        // gemm LDS pitch (ushorts): 16B-aligned rows

typedef unsigned int uint;
typedef unsigned short ushort;
typedef __attribute__((ext_vector_type(8))) short bf16x8;   // 8 bf16 (4 VGPRs)
typedef __attribute__((ext_vector_type(4))) float f32x4;

__device__ __forceinline__ ushort f2bf(float x) {
  uint u = __float_as_uint(x);
  u += 0x7fff + ((u >> 16) & 1);   // RNE
  return (ushort)(u >> 16);
}
__device__ __forceinline__ ushort f2bf_r(float x) {   // round-half-away, 2 insts
  return (ushort)((__float_as_uint(x) + 0x8000u) >> 16);
}
__device__ __forceinline__ float bf2f(ushort h) {
  return __uint_as_float(((uint)h) << 16);
}
// pack two f32 -> bf16 pair (a low). gfx950: single v_cvt_pk_bf16_f32.
__device__ __forceinline__ uint pk(float a, float b) {
#if __has_builtin(__builtin_amdgcn_cvt_pk_bf16_f32)
  auto r = __builtin_amdgcn_cvt_pk_bf16_f32(a, b);
  union { decltype(r) v; uint u; } x;
  x.v = r;
  return x.u;
#else
  uint ua = __float_as_uint(a) + 0x8000u;
  uint ub = __float_as_uint(b) + 0x8000u;
  return __builtin_amdgcn_perm(ub, ua, 0x07060302);
#endif
}
__device__ __forceinline__ bf16x8 as_bf(uint4 u) {
  union { uint4 a; bf16x8 b; } x; x.a = u; return x.b;
}
__device__ __forceinline__ float fexp2(float x) {
#if __has_builtin(__builtin_amdgcn_exp2f)
  return __builtin_amdgcn_exp2f(x);   // raw v_exp_f32
#else
  return __exp2f(x);
#endif
}

// ---------------- GN pass 1: deterministic partials, plain stores ----------------
__global__ __launch_bounds__(256) void gn_part(
    const float* __restrict__ x, float* __restrict__ stats) {
  const int bg = blockIdx.x >> 3, chunk = blockIdx.x & 7;
  const float* xp = x + (size_t)bg * (CPG * HW) + chunk * 8192;
  const int tid = threadIdx.x;
  float s = 0.f, ss = 0.f;
  #pragma unroll
  for (int j = 0; j < 8; j++) {
    float4 v = ((const float4*)xp)[j * 256 + tid];
    s += (v.x + v.y) + (v.z + v.w);
    ss += (v.x * v.x + v.y * v.y) + (v.z * v.z + v.w * v.w);
  }
  #pragma unroll
  for (int off = 32; off; off >>= 1) {
    s  += __shfl_down(s, off);
    ss += __shfl_down(ss, off);
  }
  __shared__ float rs[4], rss[4];
  const int lane = tid & 63, wid = tid >> 6;
  if (lane == 0) { rs[wid] = s; rss[wid] = ss; }
  __syncthreads();
  if (tid == 0) {
    stats[(bg * 8 + chunk) * 2]     = (rs[0] + rs[1]) + (rs[2] + rs[3]);
    stats[(bg * 8 + chunk) * 2 + 1] = (rss[0] + rss[1]) + (rss[2] + rss[3]);
  }
}

// helper: (ca, cb) for channel c of batch from stats
__device__ __forceinline__ void gn_coeff(
    const float* __restrict__ stats, const float* __restrict__ w,
    const float* __restrict__ b, int batch, int c, float& ca, float& cb) {
  const int bg = batch * G + (c >> 4);
  float s = 0.f, ss = 0.f;
  #pragma unroll
  for (int k = 0; k < 8; k++) {
    s  += stats[(bg * 8 + k) * 2];
    ss += stats[(bg * 8 + k) * 2 + 1];
  }
  const float mean = s * (1.0f / 65536.0f);
  const float var  = ss * (1.0f / 65536.0f) - mean * mean;
  const float inv  = rsqrtf(var + EPS);
  ca = w[c] * inv;
  cb = b[c] - mean * ca;
}

// ---------------- MFMA GEMM with fused GroupNorm: qkv = W @ gn(x) ----------------
// 2 m-tiles per block (M=128) sharing one staged X panel; X b-fragments loaded
// once and fed to both m-halves (32 MFMA/wave). blockIdx.y==1 is exactly the
// K block -> written directly into transposed kt[bh][e][c]; Q/V into qkvb.
__global__ __launch_bounds__(256) void qkv_gemm(
    const float* __restrict__ x, const float* __restrict__ stats,
    const float* __restrict__ gnw, const float* __restrict__ gnb,
    const float* __restrict__ w, const float* __restrict__ bias,
    ushort* __restrict__ qkvb, ushort* __restrict__ kt) {
  const int b = blockIdx.z, my = blockIdx.y, n0 = blockIdx.x * 64;
  const int m0 = my * 128;
  const int tid = threadIdx.x, lane = tid & 63, wv = tid >> 6;
  const int li = lane & 15, g = lane >> 4;
  __shared__ ushort Ws[128][GP];
  __shared__ ushort Xs[64][GP];
  __shared__ float CA[C], CB[C];

  if (tid < C) gn_coeff(stats, gnw, gnb, b, tid, CA[tid], CB[tid]);
  __syncthreads();

  // stage both W panels: thread -> (row, 32-col chunk); fp32->bf16
  {
    const int row = tid >> 2, c0 = (tid & 3) * 32;
    #pragma unroll
    for (int mh = 0; mh < 2; mh++) {
      const float* wr = w + (size_t)(m0 + mh * 64 + row) * C + c0;
      #pragma unroll
      for (int k = 0; k < 4; k++) {
        float4 f0 = ((const float4*)wr)[k * 2];
        float4 f1 = ((const float4*)wr)[k * 2 + 1];
        uint4 u = {pk(f0.x, f0.y), pk(f0.z, f0.w), pk(f1.x, f1.y), pk(f1.z, f1.w)};
        *(uint4*)&Ws[mh * 64 + row][c0 + k * 8] = u;
      }
    }
  }
  // stage X transposed with fused GN: Xs[n][c] = bf16(x*ca + cb)
  {
    const int nX = tid & 63, c0 = (tid >> 6) * 32;
    const float* xb = x + (size_t)(b * C + c0) * HW + n0 + nX;
    #pragma unroll
    for (int k = 0; k < 4; k++) {
      float xv[8];
      #pragma unroll
      for (int j = 0; j < 8; j++) {
        int c = c0 + k * 8 + j;
        xv[j] = fmaf(xb[(size_t)(k * 8 + j) * HW], CA[c], CB[c]);
      }
      uint4 u = {pk(xv[0], xv[1]), pk(xv[2], xv[3]), pk(xv[4], xv[5]), pk(xv[6], xv[7])};
      *(uint4*)&Xs[nX][c0 + k * 8] = u;
    }
  }
  __syncthreads();

  f32x4 acc[2][4];
  #pragma unroll
  for (int mh = 0; mh < 2; mh++)
    #pragma unroll
    for (int nt = 0; nt < 4; nt++) acc[mh][nt] = (f32x4){0.f, 0.f, 0.f, 0.f};
  #pragma unroll
  for (int kk = 0; kk < 4; kk++) {
    bf16x8 af0 = *(const bf16x8*)&Ws[wv * 16 + li][kk * 32 + g * 8];
    bf16x8 af1 = *(const bf16x8*)&Ws[64 + wv * 16 + li][kk * 32 + g * 8];
    #pragma unroll
    for (int nt = 0; nt < 4; nt++) {
      bf16x8 bfr = *(const bf16x8*)&Xs[nt * 16 + li][kk * 32 + g * 8];
      acc[0][nt] = __builtin_amdgcn_mfma_f32_16x16x32_bf16(af0, bfr, acc[0][nt], 0, 0, 0);
      acc[1][nt] = __builtin_amdgcn_mfma_f32_16x16x32_bf16(af1, bfr, acc[1][nt], 0, 0, 0);
    }
  }
  #pragma unroll
  for (int mh = 0; mh < 2; mh++) {
    const int ob = m0 + mh * 64 + wv * 16 + g * 4;
    if (my == 1) {
      // K channels (rows 128..255): write transposed kt[b*NH+h][e][c_local]
      const int ck = ob - C;
      const int h  = ck >> 5;
      const int cl = ck & 31;
      ushort* ktp = kt + (size_t)(b * NH + h) * HW * HD;
      #pragma unroll
      for (int r = 0; r < 4; r++) {
        float bi = bias[ob + r];
        #pragma unroll
        for (int nt = 0; nt < 4; nt++) {
          int e = n0 + nt * 16 + li;
          ktp[(size_t)e * HD + cl + r] = f2bf(acc[mh][nt][r] + bi);
        }
      }
    } else {
      #pragma unroll
      for (int r = 0; r < 4; r++) {
        float bi = bias[ob + r];
        #pragma unroll
        for (int nt = 0; nt < 4; nt++) {
          qkvb[(size_t)(b * 3 * C + ob + r) * HW + n0 + nt * 16 + li] = f2bf(acc[mh][nt][r] + bi);
        }
      }
    }
  }
}

// ---------------- MFMA flash attention: r8-exact (separate LDS arrays) ----------------
// block = 8 waves x 32 q = 128 q. Wave-group A (waves 0-3) does keys 0..2047,
// group B (waves 4-7) keys 2048..4095; each group shares a double-buffered LDS
// K/V tile stream. Merge: partner-wave (w ^ 4) partial exchange via LDS.
// S^T = K^T Q; P stays in registers (sigma absorbed in V ds_read addressing).
__global__ __launch_bounds__(512, 4) void attn_kernel(
    ushort* __restrict__ qkv, const ushort* __restrict__ kt) {
  const int bh = blockIdx.y, b = bh >> 2, h = bh & 3;
  const int tid = threadIdx.x, lane = tid & 63, wv = tid >> 6;
  const int li = lane & 15, g = lane >> 4;
  const int grp = wv >> 2, w4 = wv & 3;
  ushort* qp = qkv + (size_t)(b * 3 * C + h * HD) * HW;
  const ushort* vpl = qkv + (size_t)(b * 3 * C + 2 * C + h * HD) * HW;
  const ushort* ktp = kt + (size_t)bh * HW * HD;
  const int d0 = blockIdx.x * 128 + w4 * 32;

  __shared__ ushort Ks[2][2][32][40];   // [grp][buf][e][c]
  __shared__ ushort Vs[2][2][32][40];   // [grp][buf][c][e]
  __shared__ float OP[8][64][19];       // merge: 16 O + 2 l, odd pitch

  // Q B-fragments (2 d-tiles), prescaled by SCALE*log2(e)
  const float qs = SCALE * LOG2E;
  bf16x8 qf[2];
  #pragma unroll
  for (int dt = 0; dt < 2; dt++) {
    int d = d0 + dt * 16 + li;
    float qv[8];
    #pragma unroll
    for (int j = 0; j < 8; j++)
      qv[j] = bf2f(qp[(size_t)(g * 8 + j) * HW + d]) * qs;
    uint4 qu = {pk(qv[0], qv[1]), pk(qv[2], qv[3]), pk(qv[4], qv[5]), pk(qv[6], qv[7])};
    qf[dt] = as_bf(qu);
  }

  f32x4 O[2][2];
  #pragma unroll
  for (int dt = 0; dt < 2; dt++)
    #pragma unroll
    for (int ct = 0; ct < 2; ct++) O[dt][ct] = (f32x4){0.f, 0.f, 0.f, 0.f};
  f32x4 lacc[2] = {(f32x4){0.f, 0.f, 0.f, 0.f}, (f32x4){0.f, 0.f, 0.f, 0.f}};
  const uint one2 = 0x3F803F80u;
  const bf16x8 ones = as_bf((uint4){one2, one2, one2, one2});

  // staging: group-local threads 0..127 stage K, 128..255 stage V
  const int gt = tid & 255;
  const bool isK = gt < 128;
  const int t2 = gt & 127;
  const int srow = t2 >> 2, scol8 = (t2 & 3) * 8;
  const ushort* gK = ktp + (size_t)(grp * 64) * 1024 + t2 * 8;       // + n*1024
  const ushort* gV = vpl + (size_t)srow * HW + grp * 2048 + scol8;   // + n*32

  uint4 st = isK ? *(const uint4*)&gK[0] : *(const uint4*)&gV[0];
  if (isK) *(uint4*)&Ks[grp][0][srow][scol8] = st;
  else     *(uint4*)&Vs[grp][0][srow][scol8] = st;
  st = isK ? *(const uint4*)&gK[1024] : *(const uint4*)&gV[32];
  __syncthreads();

  for (int it = 0; it < 64; it++) {
    const int cur = it & 1, nxt = cur ^ 1;
    // store tile it+1 (loaded last iter) into the other buffer
    if (isK) *(uint4*)&Ks[grp][nxt][srow][scol8] = st;
    else     *(uint4*)&Vs[grp][nxt][srow][scol8] = st;

    // fragments from current buffer
    bf16x8 kf0 = *(const bf16x8*)&Ks[grp][cur][li][g * 8];
    bf16x8 kf1 = *(const bf16x8*)&Ks[grp][cur][16 + li][g * 8];
    uint2 va0 = *(const uint2*)&Vs[grp][cur][li][4 * g];
    uint2 va1 = *(const uint2*)&Vs[grp][cur][li][16 + 4 * g];
    uint2 vb0 = *(const uint2*)&Vs[grp][cur][16 + li][4 * g];
    uint2 vb1 = *(const uint2*)&Vs[grp][cur][16 + li][16 + 4 * g];
    bf16x8 vf0 = as_bf((uint4){va0.x, va0.y, va1.x, va1.y});
    bf16x8 vf1 = as_bf((uint4){vb0.x, vb0.y, vb1.x, vb1.y});

    // prefetch tile it+2 into regs (wraps in-range on last iters: dead data)
    const int tn = (it + 2) & 63;
    st = isK ? *(const uint4*)&gK[(size_t)tn * 1024] : *(const uint4*)&gV[tn * 32];

    const f32x4 z = (f32x4){0.f, 0.f, 0.f, 0.f};
    #pragma unroll
    for (int dt = 0; dt < 2; dt++) {
      f32x4 s0 = __builtin_amdgcn_mfma_f32_16x16x32_bf16(kf0, qf[dt], z, 0, 0, 0);
      f32x4 s1 = __builtin_amdgcn_mfma_f32_16x16x32_bf16(kf1, qf[dt], z, 0, 0, 0);
      float p0 = fexp2(s0[0]), p1 = fexp2(s0[1]), p2 = fexp2(s0[2]), p3 = fexp2(s0[3]);
      float p4 = fexp2(s1[0]), p5 = fexp2(s1[1]), p6 = fexp2(s1[2]), p7 = fexp2(s1[3]);
      // sigma: k=g*8+{0..3} -> e=4g+{0..3}; k=g*8+{4..7} -> e=16+4g+{0..3}
      uint4 pu = {pk(p0, p1), pk(p2, p3), pk(p4, p5), pk(p6, p7)};
      bf16x8 pf = as_bf(pu);
      lacc[dt] = __builtin_amdgcn_mfma_f32_16x16x32_bf16(ones, pf, lacc[dt], 0, 0, 0);
      O[dt][0] = __builtin_amdgcn_mfma_f32_16x16x32_bf16(vf0, pf, O[dt][0], 0, 0, 0);
      O[dt][1] = __builtin_amdgcn_mfma_f32_16x16x32_bf16(vf1, pf, O[dt][1], 0, 0, 0);
    }
    __syncthreads();
  }

  // ---- split-K merge with partner wave (w ^ 4); wave writes channel half ct=grp ----
  #pragma unroll
  for (int dt = 0; dt < 2; dt++) {
    #pragma unroll
    for (int ct = 0; ct < 2; ct++)
      #pragma unroll
      for (int r = 0; r < 4; r++) OP[wv][lane][dt * 8 + ct * 4 + r] = O[dt][ct][r];
    OP[wv][lane][16 + dt] = lacc[dt][0];
  }
  __syncthreads();
  const int pw = wv ^ 4;
  #pragma unroll
  for (int dt = 0; dt < 2; dt++) {
    const float inv = 1.0f / (lacc[dt][0] + OP[pw][lane][16 + dt]);
    const int d = d0 + dt * 16 + li;
    #pragma unroll
    for (int r = 0; r < 4; r++) {
      float val = O[dt][grp][r] + OP[pw][lane][dt * 8 + grp * 4 + r];
      qp[(size_t)(grp * 16 + g * 4 + r) * HW + d] = f2bf_r(val * inv);
    }
  }
}

// ---------------- MFMA GEMM proj + bias + fp32 GN residual, fp32 out ----------------
__global__ __launch_bounds__(256) void proj_gemm(
    const ushort* __restrict__ qkvb, const float* __restrict__ w,
    const float* __restrict__ bias, const float* __restrict__ x,
    const float* __restrict__ stats, const float* __restrict__ gnw,
    const float* __restrict__ gnb, float* __restrict__ out) {
  const int b = blockIdx.z, m0 = blockIdx.y * 64, n0 = blockIdx.x * 64;
  const int tid = threadIdx.x, lane = tid & 63, wv = tid >> 6;
  const int li = lane & 15, g = lane >> 4;
  __shared__ ushort Ws[64][GP];
  __shared__ ushort Xs[64][GP];
  __shared__ float CA[64], CB[64];

  if (tid < 64) gn_coeff(stats, gnw, gnb, b, m0 + tid, CA[tid], CB[tid]);

  {
    const int row = tid >> 2, c0 = (tid & 3) * 32;
    const float* wr = w + (size_t)(m0 + row) * C + c0;
    #pragma unroll
    for (int k = 0; k < 4; k++) {
      float4 f0 = ((const float4*)wr)[k * 2];
      float4 f1 = ((const float4*)wr)[k * 2 + 1];
      uint4 u = {pk(f0.x, f0.y), pk(f0.z, f0.w), pk(f1.x, f1.y), pk(f1.z, f1.w)};
      *(uint4*)&Ws[row][c0 + k * 8] = u;
    }
  }
  {
    const int nX = tid & 63, c0 = (tid >> 6) * 32;
    const ushort* xb = qkvb + (size_t)(b * 3 * C + c0) * HW + n0 + nX;
    #pragma unroll
    for (int k = 0; k < 4; k++) {
      ushort t8[8];
      #pragma unroll
      for (int j = 0; j < 8; j++) t8[j] = xb[(size_t)(k * 8 + j) * HW];
      uint4 u;
      u.x = t8[0] | ((uint)t8[1] << 16);
      u.y = t8[2] | ((uint)t8[3] << 16);
      u.z = t8[4] | ((uint)t8[5] << 16);
      u.w = t8[6] | ((uint)t8[7] << 16);
      *(uint4*)&Xs[nX][c0 + k * 8] = u;
    }
  }
  __syncthreads();

  f32x4 acc[4];
  #pragma unroll
  for (int nt = 0; nt < 4; nt++) acc[nt] = (f32x4){0.f, 0.f, 0.f, 0.f};
  #pragma unroll
  for (int kk = 0; kk < 4; kk++) {
    bf16x8 af = *(const bf16x8*)&Ws[wv * 16 + li][kk * 32 + g * 8];
    #pragma unroll
    for (int nt = 0; nt < 4; nt++) {
      bf16x8 bfr = *(const bf16x8*)&Xs[nt * 16 + li][kk * 32 + g * 8];
      acc[nt] = __builtin_amdgcn_mfma_f32_16x16x32_bf16(af, bfr, acc[nt], 0, 0, 0);
    }
  }
  const int ob = m0 + wv * 16 + g * 4;
  #pragma unroll
  for (int r = 0; r < 4; r++) {
    const float bi = bias[ob + r];
    const float ca = CA[wv * 16 + g * 4 + r], cb = CB[wv * 16 + g * 4 + r];
    #pragma unroll
    for (int nt = 0; nt < 4; nt++) {
      size_t idx = (size_t)(b * C + ob + r) * HW + n0 + nt * 16 + li;
      out[idx] = acc[nt][r] + bi + fmaf(x[idx], ca, cb);
    }
  }
}

extern "C" void kernel_launch(void* const* d_in, const int* in_sizes, int n_in,
                              void* d_out, int out_size, void* d_ws, size_t ws_size,
                              hipStream_t stream) {
  const float* x     = (const float*)d_in[0];
  const float* gn_w  = (const float*)d_in[1];
  const float* gn_b  = (const float*)d_in[2];
  const float* qkv_w = (const float*)d_in[3];
  const float* qkv_b = (const float*)d_in[4];
  const float* pw    = (const float*)d_in[5];
  const float* pb    = (const float*)d_in[6];
  float* out = (float*)d_out;

  float*  stats = (float*)d_ws;                              // 512 floats (pad to 4 KB)
  ushort* qkvb  = (ushort*)((char*)d_ws + 4096);             // 12 MB bf16 (K-plane unused)
  ushort* kt    = qkvb + (size_t)BATCH * 3 * C * HW;         // 4 MB  [bh][e][c]

  gn_part<<<dim3(256), dim3(256), 0, stream>>>(x, stats);
  qkv_gemm<<<dim3(HW / 64, 3, BATCH), dim3(256), 0, stream>>>(
      x, stats, gn_w, gn_b, qkv_w, qkv_b, qkvb, kt);
  attn_kernel<<<dim3(HW / 128, BATCH * NH), dim3(512), 0, stream>>>(qkvb, kt);
  proj_gemm<<<dim3(HW / 64, 2, BATCH), dim3(256), 0, stream>>>(
      qkvb, pw, pb, x, stats, gn_w, gn_b, out);
}

// Round 14
// 141.717 us; speedup vs baseline: 1.2060x; 1.0021x over previous
//
#include <hip/hip_runtime.h>
#include <math.h>

#define BATCH 4
#define C 128
#define HW 4096
#define G 8
#define CPG 16
#define NH 4
#define HD 32
#define EPS 1e-5f
#define SCALE 0.08838834764831845f   // 128^-0.5
#define LOG2E 1.44269504088896340f
#define GP 136                        // gemm LDS pitch (ushorts): 16B-aligned rows

typedef unsigned int uint;
typedef unsigned short ushort;
typedef __attribute__((ext_vector_type(8))) short bf16x8;   // 8 bf16 (4 VGPRs)
typedef __attribute__((ext_vector_type(4))) float f32x4;

__device__ __forceinline__ ushort f2bf(float x) {
  uint u = __float_as_uint(x);
  u += 0x7fff + ((u >> 16) & 1);   // RNE
  return (ushort)(u >> 16);
}
__device__ __forceinline__ ushort f2bf_r(float x) {   // round-half-away, 2 insts
  return (ushort)((__float_as_uint(x) + 0x8000u) >> 16);
}
__device__ __forceinline__ float bf2f(ushort h) {
  return __uint_as_float(((uint)h) << 16);
}
// pack two f32 -> bf16 pair (a low). gfx950: single v_cvt_pk_bf16_f32.
__device__ __forceinline__ uint pk(float a, float b) {
#if __has_builtin(__builtin_amdgcn_cvt_pk_bf16_f32)
  auto r = __builtin_amdgcn_cvt_pk_bf16_f32(a, b);
  union { decltype(r) v; uint u; } x;
  x.v = r;
  return x.u;
#else
  uint ua = __float_as_uint(a) + 0x8000u;
  uint ub = __float_as_uint(b) + 0x8000u;
  return __builtin_amdgcn_perm(ub, ua, 0x07060302);
#endif
}
__device__ __forceinline__ bf16x8 as_bf(uint4 u) {
  union { uint4 a; bf16x8 b; } x; x.a = u; return x.b;
}
__device__ __forceinline__ float fexp2(float x) {
#if __has_builtin(__builtin_amdgcn_exp2f)
  return __builtin_amdgcn_exp2f(x);   // raw v_exp_f32
#else
  return __exp2f(x);
#endif
}

// ---------------- GN pass 1: deterministic partials, plain stores ----------------
__global__ __launch_bounds__(256) void gn_part(
    const float* __restrict__ x, float* __restrict__ stats) {
  const int bg = blockIdx.x >> 3, chunk = blockIdx.x & 7;
  const float* xp = x + (size_t)bg * (CPG * HW) + chunk * 8192;
  const int tid = threadIdx.x;
  float s = 0.f, ss = 0.f;
  #pragma unroll
  for (int j = 0; j < 8; j++) {
    float4 v = ((const float4*)xp)[j * 256 + tid];
    s += (v.x + v.y) + (v.z + v.w);
    ss += (v.x * v.x + v.y * v.y) + (v.z * v.z + v.w * v.w);
  }
  #pragma unroll
  for (int off = 32; off; off >>= 1) {
    s  += __shfl_down(s, off);
    ss += __shfl_down(ss, off);
  }
  __shared__ float rs[4], rss[4];
  const int lane = tid & 63, wid = tid >> 6;
  if (lane == 0) { rs[wid] = s; rss[wid] = ss; }
  __syncthreads();
  if (tid == 0) {
    stats[(bg * 8 + chunk) * 2]     = (rs[0] + rs[1]) + (rs[2] + rs[3]);
    stats[(bg * 8 + chunk) * 2 + 1] = (rss[0] + rss[1]) + (rss[2] + rss[3]);
  }
}

// helper: (ca, cb) for channel c of batch from stats
__device__ __forceinline__ void gn_coeff(
    const float* __restrict__ stats, const float* __restrict__ w,
    const float* __restrict__ b, int batch, int c, float& ca, float& cb) {
  const int bg = batch * G + (c >> 4);
  float s = 0.f, ss = 0.f;
  #pragma unroll
  for (int k = 0; k < 8; k++) {
    s  += stats[(bg * 8 + k) * 2];
    ss += stats[(bg * 8 + k) * 2 + 1];
  }
  const float mean = s * (1.0f / 65536.0f);
  const float var  = ss * (1.0f / 65536.0f) - mean * mean;
  const float inv  = rsqrtf(var + EPS);
  ca = w[c] * inv;
  cb = b[c] - mean * ca;
}

// ---------------- MFMA GEMM with fused GroupNorm: qkv = W @ gn(x) ----------------
// 2 m-tiles per block (M=128) sharing one staged X panel; blockIdx.y==1 is the
// K block -> written directly into transposed kt[bh][e][c]; Q/V into qkvb.
__global__ __launch_bounds__(256) void qkv_gemm(
    const float* __restrict__ x, const float* __restrict__ stats,
    const float* __restrict__ gnw, const float* __restrict__ gnb,
    const float* __restrict__ w, const float* __restrict__ bias,
    ushort* __restrict__ qkvb, ushort* __restrict__ kt) {
  const int b = blockIdx.z, my = blockIdx.y, n0 = blockIdx.x * 64;
  const int m0 = my * 128;
  const int tid = threadIdx.x, lane = tid & 63, wv = tid >> 6;
  const int li = lane & 15, g = lane >> 4;
  __shared__ ushort Ws[128][GP];
  __shared__ ushort Xs[64][GP];
  __shared__ float CA[C], CB[C];

  if (tid < C) gn_coeff(stats, gnw, gnb, b, tid, CA[tid], CB[tid]);
  __syncthreads();

  {
    const int row = tid >> 2, c0 = (tid & 3) * 32;
    #pragma unroll
    for (int mh = 0; mh < 2; mh++) {
      const float* wr = w + (size_t)(m0 + mh * 64 + row) * C + c0;
      #pragma unroll
      for (int k = 0; k < 4; k++) {
        float4 f0 = ((const float4*)wr)[k * 2];
        float4 f1 = ((const float4*)wr)[k * 2 + 1];
        uint4 u = {pk(f0.x, f0.y), pk(f0.z, f0.w), pk(f1.x, f1.y), pk(f1.z, f1.w)};
        *(uint4*)&Ws[mh * 64 + row][c0 + k * 8] = u;
      }
    }
  }
  {
    const int nX = tid & 63, c0 = (tid >> 6) * 32;
    const float* xb = x + (size_t)(b * C + c0) * HW + n0 + nX;
    #pragma unroll
    for (int k = 0; k < 4; k++) {
      float xv[8];
      #pragma unroll
      for (int j = 0; j < 8; j++) {
        int c = c0 + k * 8 + j;
        xv[j] = fmaf(xb[(size_t)(k * 8 + j) * HW], CA[c], CB[c]);
      }
      uint4 u = {pk(xv[0], xv[1]), pk(xv[2], xv[3]), pk(xv[4], xv[5]), pk(xv[6], xv[7])};
      *(uint4*)&Xs[nX][c0 + k * 8] = u;
    }
  }
  __syncthreads();

  f32x4 acc[2][4];
  #pragma unroll
  for (int mh = 0; mh < 2; mh++)
    #pragma unroll
    for (int nt = 0; nt < 4; nt++) acc[mh][nt] = (f32x4){0.f, 0.f, 0.f, 0.f};
  #pragma unroll
  for (int kk = 0; kk < 4; kk++) {
    bf16x8 af0 = *(const bf16x8*)&Ws[wv * 16 + li][kk * 32 + g * 8];
    bf16x8 af1 = *(const bf16x8*)&Ws[64 + wv * 16 + li][kk * 32 + g * 8];
    #pragma unroll
    for (int nt = 0; nt < 4; nt++) {
      bf16x8 bfr = *(const bf16x8*)&Xs[nt * 16 + li][kk * 32 + g * 8];
      acc[0][nt] = __builtin_amdgcn_mfma_f32_16x16x32_bf16(af0, bfr, acc[0][nt], 0, 0, 0);
      acc[1][nt] = __builtin_amdgcn_mfma_f32_16x16x32_bf16(af1, bfr, acc[1][nt], 0, 0, 0);
    }
  }
  #pragma unroll
  for (int mh = 0; mh < 2; mh++) {
    const int ob = m0 + mh * 64 + wv * 16 + g * 4;
    if (my == 1) {
      const int ck = ob - C;
      const int h  = ck >> 5;
      const int cl = ck & 31;
      ushort* ktp = kt + (size_t)(b * NH + h) * HW * HD;
      #pragma unroll
      for (int r = 0; r < 4; r++) {
        float bi = bias[ob + r];
        #pragma unroll
        for (int nt = 0; nt < 4; nt++) {
          int e = n0 + nt * 16 + li;
          ktp[(size_t)e * HD + cl + r] = f2bf(acc[mh][nt][r] + bi);
        }
      }
    } else {
      #pragma unroll
      for (int r = 0; r < 4; r++) {
        float bi = bias[ob + r];
        #pragma unroll
        for (int nt = 0; nt < 4; nt++) {
          qkvb[(size_t)(b * 3 * C + ob + r) * HW + n0 + nt * 16 + li] = f2bf(acc[mh][nt][r] + bi);
        }
      }
    }
  }
}

// ---------------- MFMA flash attention ----------------
// r12 structure; V staged into LDS pre-sigma-permuted so V fragment reads are
// 2x b128 (was 8x b64) — halves V LDS read traffic. All math identical.
__global__ __launch_bounds__(512, 4) void attn_kernel(
    ushort* __restrict__ qkv, const ushort* __restrict__ kt) {
  const int bh = blockIdx.y, b = bh >> 2, h = bh & 3;
  const int tid = threadIdx.x, lane = tid & 63, wv = tid >> 6;
  const int li = lane & 15, g = lane >> 4;
  const int grp = wv >> 2, w4 = wv & 3;
  ushort* qp = qkv + (size_t)(b * 3 * C + h * HD) * HW;
  const ushort* vpl = qkv + (size_t)(b * 3 * C + 2 * C + h * HD) * HW;
  const ushort* ktp = kt + (size_t)bh * HW * HD;
  const int d0 = blockIdx.x * 128 + w4 * 32;

  __shared__ ushort Ks[2][2][32][40];   // [grp][buf][e][c]
  __shared__ ushort Vs[2][2][32][40];   // [grp][buf][c][p]  (p = sigma(e))
  __shared__ float OP[8][64][19];       // merge: 16 O + 2 l, odd pitch

  // Q B-fragments (2 d-tiles), prescaled by SCALE*log2(e)
  const float qs = SCALE * LOG2E;
  bf16x8 qf[2];
  #pragma unroll
  for (int dt = 0; dt < 2; dt++) {
    int d = d0 + dt * 16 + li;
    float qv[8];
    #pragma unroll
    for (int j = 0; j < 8; j++)
      qv[j] = bf2f(qp[(size_t)(g * 8 + j) * HW + d]) * qs;
    uint4 qu = {pk(qv[0], qv[1]), pk(qv[2], qv[3]), pk(qv[4], qv[5]), pk(qv[6], qv[7])};
    qf[dt] = as_bf(qu);
  }

  f32x4 O[2][2];
  #pragma unroll
  for (int dt = 0; dt < 2; dt++)
    #pragma unroll
    for (int ct = 0; ct < 2; ct++) O[dt][ct] = (f32x4){0.f, 0.f, 0.f, 0.f};
  f32x4 lacc[2] = {(f32x4){0.f, 0.f, 0.f, 0.f}, (f32x4){0.f, 0.f, 0.f, 0.f}};
  const uint one2 = 0x3F803F80u;
  const bf16x8 ones = as_bf((uint4){one2, one2, one2, one2});

  // staging: group-local threads 0..127 stage K, 128..255 stage V
  const int gt = tid & 255;
  const bool isK = gt < 128;
  const int t2 = gt & 127;
  const int srow = t2 >> 2, scol8 = (t2 & 3) * 8;
  // V sigma write positions: e-octet q=(t2&3) -> quads at p0 and p0+8
  const int q4 = t2 & 3;
  const int p0 = 16 * (q4 & 1) + 4 * (q4 >> 1);
  const ushort* gK = ktp + (size_t)(grp * 64) * 1024 + t2 * 8;       // + n*1024
  const ushort* gV = vpl + (size_t)srow * HW + grp * 2048 + scol8;   // + n*32

  uint4 st = isK ? *(const uint4*)&gK[0] : *(const uint4*)&gV[0];
  if (isK) {
    *(uint4*)&Ks[grp][0][srow][scol8] = st;
  } else {
    *(uint2*)&Vs[grp][0][srow][p0]     = (uint2){st.x, st.y};
    *(uint2*)&Vs[grp][0][srow][p0 + 8] = (uint2){st.z, st.w};
  }
  st = isK ? *(const uint4*)&gK[1024] : *(const uint4*)&gV[32];
  __syncthreads();

  for (int it = 0; it < 64; it++) {
    const int cur = it & 1, nxt = cur ^ 1;
    // store tile it+1 (loaded last iter) into the other buffer
    if (isK) {
      *(uint4*)&Ks[grp][nxt][srow][scol8] = st;
    } else {
      *(uint2*)&Vs[grp][nxt][srow][p0]     = (uint2){st.x, st.y};
      *(uint2*)&Vs[grp][nxt][srow][p0 + 8] = (uint2){st.z, st.w};
    }

    // fragments from current buffer (all b128 now)
    bf16x8 kf0 = *(const bf16x8*)&Ks[grp][cur][li][g * 8];
    bf16x8 kf1 = *(const bf16x8*)&Ks[grp][cur][16 + li][g * 8];
    bf16x8 vf0 = *(const bf16x8*)&Vs[grp][cur][li][g * 8];
    bf16x8 vf1 = *(const bf16x8*)&Vs[grp][cur][16 + li][g * 8];

    // prefetch tile it+2 into regs (wraps in-range on last iters: dead data)
    const int tn = (it + 2) & 63;
    st = isK ? *(const uint4*)&gK[(size_t)tn * 1024] : *(const uint4*)&gV[tn * 32];

    const f32x4 z = (f32x4){0.f, 0.f, 0.f, 0.f};
    #pragma unroll
    for (int dt = 0; dt < 2; dt++) {
      f32x4 s0 = __builtin_amdgcn_mfma_f32_16x16x32_bf16(kf0, qf[dt], z, 0, 0, 0);
      f32x4 s1 = __builtin_amdgcn_mfma_f32_16x16x32_bf16(kf1, qf[dt], z, 0, 0, 0);
      float p0f = fexp2(s0[0]), p1f = fexp2(s0[1]), p2f = fexp2(s0[2]), p3f = fexp2(s0[3]);
      float p4f = fexp2(s1[0]), p5f = fexp2(s1[1]), p6f = fexp2(s1[2]), p7f = fexp2(s1[3]);
      // sigma: k=g*8+{0..3} -> e=4g+{0..3}; k=g*8+{4..7} -> e=16+4g+{0..3}
      uint4 pu = {pk(p0f, p1f), pk(p2f, p3f), pk(p4f, p5f), pk(p6f, p7f)};
      bf16x8 pf = as_bf(pu);
      lacc[dt] = __builtin_amdgcn_mfma_f32_16x16x32_bf16(ones, pf, lacc[dt], 0, 0, 0);
      O[dt][0] = __builtin_amdgcn_mfma_f32_16x16x32_bf16(vf0, pf, O[dt][0], 0, 0, 0);
      O[dt][1] = __builtin_amdgcn_mfma_f32_16x16x32_bf16(vf1, pf, O[dt][1], 0, 0, 0);
    }
    __syncthreads();
  }

  // ---- split-K merge with partner wave (w ^ 4); wave writes channel half ct=grp ----
  #pragma unroll
  for (int dt = 0; dt < 2; dt++) {
    #pragma unroll
    for (int ct = 0; ct < 2; ct++)
      #pragma unroll
      for (int r = 0; r < 4; r++) OP[wv][lane][dt * 8 + ct * 4 + r] = O[dt][ct][r];
    OP[wv][lane][16 + dt] = lacc[dt][0];
  }
  __syncthreads();
  const int pw = wv ^ 4;
  #pragma unroll
  for (int dt = 0; dt < 2; dt++) {
    const float inv = 1.0f / (lacc[dt][0] + OP[pw][lane][16 + dt]);
    const int d = d0 + dt * 16 + li;
    #pragma unroll
    for (int r = 0; r < 4; r++) {
      float val = O[dt][grp][r] + OP[pw][lane][dt * 8 + grp * 4 + r];
      qp[(size_t)(grp * 16 + g * 4 + r) * HW + d] = f2bf_r(val * inv);
    }
  }
}

// ---------------- MFMA GEMM proj + bias + fp32 GN residual, fp32 out ----------------
// M=128 merge: one block covers all output channels for a 64-n strip;
// X panel staged once, 32 MFMA/wave.
__global__ __launch_bounds__(256) void proj_gemm(
    const ushort* __restrict__ qkvb, const float* __restrict__ w,
    const float* __restrict__ bias, const float* __restrict__ x,
    const float* __restrict__ stats, const float* __restrict__ gnw,
    const float* __restrict__ gnb, float* __restrict__ out) {
  const int b = blockIdx.z, n0 = blockIdx.x * 64;
  const int tid = threadIdx.x, lane = tid & 63, wv = tid >> 6;
  const int li = lane & 15, g = lane >> 4;
  __shared__ ushort Ws[128][GP];
  __shared__ ushort Xs[64][GP];
  __shared__ float CA[C], CB[C];

  if (tid < C) gn_coeff(stats, gnw, gnb, b, tid, CA[tid], CB[tid]);

  {
    const int row = tid >> 2, c0 = (tid & 3) * 32;
    #pragma unroll
    for (int mh = 0; mh < 2; mh++) {
      const float* wr = w + (size_t)(mh * 64 + row) * C + c0;
      #pragma unroll
      for (int k = 0; k < 4; k++) {
        float4 f0 = ((const float4*)wr)[k * 2];
        float4 f1 = ((const float4*)wr)[k * 2 + 1];
        uint4 u = {pk(f0.x, f0.y), pk(f0.z, f0.w), pk(f1.x, f1.y), pk(f1.z, f1.w)};
        *(uint4*)&Ws[mh * 64 + row][c0 + k * 8] = u;
      }
    }
  }
  {
    const int nX = tid & 63, c0 = (tid >> 6) * 32;
    const ushort* xb = qkvb + (size_t)(b * 3 * C + c0) * HW + n0 + nX;
    #pragma unroll
    for (int k = 0; k < 4; k++) {
      ushort t8[8];
      #pragma unroll
      for (int j = 0; j < 8; j++) t8[j] = xb[(size_t)(k * 8 + j) * HW];
      uint4 u;
      u.x = t8[0] | ((uint)t8[1] << 16);
      u.y = t8[2] | ((uint)t8[3] << 16);
      u.z = t8[4] | ((uint)t8[5] << 16);
      u.w = t8[6] | ((uint)t8[7] << 16);
      *(uint4*)&Xs[nX][c0 + k * 8] = u;
    }
  }
  __syncthreads();

  f32x4 acc[2][4];
  #pragma unroll
  for (int mh = 0; mh < 2; mh++)
    #pragma unroll
    for (int nt = 0; nt < 4; nt++) acc[mh][nt] = (f32x4){0.f, 0.f, 0.f, 0.f};
  #pragma unroll
  for (int kk = 0; kk < 4; kk++) {
    bf16x8 af0 = *(const bf16x8*)&Ws[wv * 16 + li][kk * 32 + g * 8];
    bf16x8 af1 = *(const bf16x8*)&Ws[64 + wv * 16 + li][kk * 32 + g * 8];
    #pragma unroll
    for (int nt = 0; nt < 4; nt++) {
      bf16x8 bfr = *(const bf16x8*)&Xs[nt * 16 + li][kk * 32 + g * 8];
      acc[0][nt] = __builtin_amdgcn_mfma_f32_16x16x32_bf16(af0, bfr, acc[0][nt], 0, 0, 0);
      acc[1][nt] = __builtin_amdgcn_mfma_f32_16x16x32_bf16(af1, bfr, acc[1][nt], 0, 0, 0);
    }
  }
  #pragma unroll
  for (int mh = 0; mh < 2; mh++) {
    const int ob = mh * 64 + wv * 16 + g * 4;
    #pragma unroll
    for (int r = 0; r < 4; r++) {
      const float bi = bias[ob + r];
      const float ca = CA[ob + r], cb = CB[ob + r];
      #pragma unroll
      for (int nt = 0; nt < 4; nt++) {
        size_t idx = (size_t)(b * C + ob + r) * HW + n0 + nt * 16 + li;
        out[idx] = acc[mh][nt][r] + bi + fmaf(x[idx], ca, cb);
      }
    }
  }
}

extern "C" void kernel_launch(void* const* d_in, const int* in_sizes, int n_in,
                              void* d_out, int out_size, void* d_ws, size_t ws_size,
                              hipStream_t stream) {
  const float* x     = (const float*)d_in[0];
  const float* gn_w  = (const float*)d_in[1];
  const float* gn_b  = (const float*)d_in[2];
  const float* qkv_w = (const float*)d_in[3];
  const float* qkv_b = (const float*)d_in[4];
  const float* pw    = (const float*)d_in[5];
  const float* pb    = (const float*)d_in[6];
  float* out = (float*)d_out;

  float*  stats = (float*)d_ws;                              // 512 floats (pad to 4 KB)
  ushort* qkvb  = (ushort*)((char*)d_ws + 4096);             // 12 MB bf16 (K-plane unused)
  ushort* kt    = qkvb + (size_t)BATCH * 3 * C * HW;         // 4 MB  [bh][e][c]

  gn_part<<<dim3(256), dim3(256), 0, stream>>>(x, stats);
  qkv_gemm<<<dim3(HW / 64, 3, BATCH), dim3(256), 0, stream>>>(
      x, stats, gn_w, gn_b, qkv_w, qkv_b, qkvb, kt);
  attn_kernel<<<dim3(HW / 128, BATCH * NH), dim3(512), 0, stream>>>(qkvb, kt);
  proj_gemm<<<dim3(HW / 64, 1, BATCH), dim3(256), 0, stream>>>(
      qkvb, pw, pb, x, stats, gn_w, gn_b, out);
}